// Round 9
// baseline (1010.434 us; speedup 1.0000x reference)
//
#include <hip/hip_runtime.h>
#include <hip/hip_bf16.h>

typedef __attribute__((ext_vector_type(8))) short bfrag;
typedef __attribute__((ext_vector_type(4))) float f4;

__device__ __forceinline__ unsigned short f2bf(float f){
  unsigned b = __float_as_uint(f);
  b = (b + 0x7fffu + ((b >> 16) & 1u)) >> 16;
  return (unsigned short)b;
}
__device__ __forceinline__ unsigned pk2bf(float a, float b){
  return (unsigned)f2bf(a) | ((unsigned)f2bf(b) << 16);
}
__device__ __forceinline__ float bf2f(unsigned short u){
  return __uint_as_float(((unsigned)u) << 16);
}
__device__ __forceinline__ bfrag pack8(float4 x, float4 y){
  bfrag r;
  r[0]=(short)f2bf(x.x); r[1]=(short)f2bf(x.y); r[2]=(short)f2bf(x.z); r[3]=(short)f2bf(x.w);
  r[4]=(short)f2bf(y.x); r[5]=(short)f2bf(y.y); r[6]=(short)f2bf(y.z); r[7]=(short)f2bf(y.w);
  return r;
}

// ---------------- B pre-pack: W_full (192x128 f32) -> MFMA frag layout bf16 ----------------
__global__ __launch_bounds__(64) void k_prep(const float* __restrict__ Wf, unsigned short* __restrict__ Bpack){
  int l = threadIdx.x; int f = blockIdx.x; int ks = f >> 3; int nt = f & 7;
  int kg = l >> 4; int nn = l & 15;
#pragma unroll
  for (int j = 0; j < 8; ++j){
    int k;
    if (ks < 4) k = ks*32 + kg*8 + j;
    else        k = 128 + (ks-4)*32 + ((j>>2)<<4) + kg*4 + (j&3);
    Bpack[((size_t)f*64 + l)*8 + j] = f2bf(Wf[(size_t)k*128 + nt*16 + nn]);
  }
}

// ---------------- merged prepass: all three histograms in one launch ----------------
__global__ __launch_bounds__(256) void k_pre(const int* __restrict__ cidxe, int E,
                                             const int* __restrict__ cidxn, int NN,
                                             const int* __restrict__ nbr,
                                             int* __restrict__ ccnte, int* __restrict__ ccntn,
                                             int* __restrict__ ncnt){
  __shared__ int he[256], hn[256];
  int t = threadIdx.x;
  he[t] = 0; hn[t] = 0;
  __syncthreads();
  for (size_t i = (size_t)blockIdx.x*256 + t; i < (size_t)E; i += (size_t)gridDim.x*256){
    atomicAdd(&he[cidxe[i]], 1);
    atomicAdd(&ncnt[nbr[2*i]], 1);
  }
  for (size_t i = (size_t)blockIdx.x*256 + t; i < (size_t)NN; i += (size_t)gridDim.x*256)
    atomicAdd(&hn[cidxn[i]], 1);
  __syncthreads();
  if (he[t]) atomicAdd(&ccnte[t], he[t]);
  if (hn[t]) atomicAdd(&ccntn[t], hn[t]);
}

// ---------------- merged scans: block 0 = node-count scan (1024 thr); blocks 1,2 = 256-bin crystal scans ----------------
__global__ __launch_bounds__(1024) void k_scans(const int* __restrict__ ncnt, int NN,
                                                int* __restrict__ offs, int* __restrict__ cursor,
                                                const int* __restrict__ ccnte, const int* __restrict__ ccntn,
                                                int* __restrict__ ceoffs, int* __restrict__ cecur,
                                                int* __restrict__ cnoffs, int* __restrict__ cncur){
  int tid = threadIdx.x;
  if (blockIdx.x == 0){
    __shared__ int part[1024];
    int chunk = (NN + 1023) >> 10;
    int base = tid*chunk;
    int s = 0;
    for (int i = 0; i < chunk; ++i){ int p = base + i; if (p < NN) s += ncnt[p]; }
    part[tid] = s;
    __syncthreads();
    for (int d = 1; d < 1024; d <<= 1){
      int v = (tid >= d) ? part[tid - d] : 0;
      __syncthreads();
      part[tid] += v;
      __syncthreads();
    }
    int run = (tid == 0) ? 0 : part[tid-1];
    for (int i = 0; i < chunk; ++i){
      int p = base + i;
      if (p < NN){ offs[p] = run; cursor[p] = run; run += ncnt[p]; }
    }
    if (tid == 1023) offs[NN] = part[1023];
  } else {
    __shared__ int sh[256];
    const int* cnt = (blockIdx.x == 2) ? ccntn : ccnte;
    int* off = (blockIdx.x == 2) ? cnoffs : ceoffs;
    int* cur = (blockIdx.x == 2) ? cncur  : cecur;
    int v = 0;
    if (tid < 256){ v = cnt[tid]; sh[tid] = v; }
    __syncthreads();
    for (int d = 1; d < 256; d <<= 1){
      int x = (tid >= d && tid < 256) ? sh[tid - d] : 0;
      __syncthreads();
      if (tid < 256) sh[tid] += x;
      __syncthreads();
    }
    if (tid < 256){
      off[tid] = sh[tid] - v; cur[tid] = sh[tid] - v;
      if (tid == 255) off[256] = sh[255];
    }
  }
}

// ---------------- MERGED CSR scatter + crystal-list build ----------------
__global__ __launch_bounds__(256) void k_scatter2(const int* __restrict__ nbr, const int* __restrict__ cidxe,
                                                  int E, int* __restrict__ cursor, int4* __restrict__ edat,
                                                  int* __restrict__ gcur, int* __restrict__ celist){
  __shared__ int lhist[256], lbase[256], lcur[256];
  int t = threadIdx.x;
  lhist[t] = 0; lcur[t] = 0;
  __syncthreads();
  int base = blockIdx.x*1024;
  int end = min(base + 1024, E);
  for (int i = base + t; i < end; i += 256) atomicAdd(&lhist[cidxe[i]], 1);
  __syncthreads();
  if (lhist[t]) lbase[t] = atomicAdd(&gcur[t], lhist[t]);
  __syncthreads();
  for (int i = base + t; i < end; i += 256){
    int cr = cidxe[i];
    int n = nbr[2*(size_t)i];
    int j = nbr[2*(size_t)i + 1];
    int pos = atomicAdd(&cursor[n], 1);
    edat[pos] = make_int4(n, j, i, cr);
    int lp = atomicAdd(&lcur[cr], 1);
    celist[lbase[cr] + lp] = pos;
  }
}

// ---------------- hierarchical crystal scatter (node list) ----------------
__global__ __launch_bounds__(256) void k_cscatter(const int* __restrict__ idx, int n,
                                                  int* __restrict__ gcur, int* __restrict__ outl){
  __shared__ int lhist[256], lbase[256], lcur[256];
  int t = threadIdx.x;
  lhist[t] = 0; lcur[t] = 0;
  __syncthreads();
  int base = blockIdx.x*4096;
  int end = min(base + 4096, n);
  for (int i = base + t; i < end; i += 256) atomicAdd(&lhist[idx[i]], 1);
  __syncthreads();
  if (lhist[t]) lbase[t] = atomicAdd(&gcur[t], lhist[t]);
  __syncthreads();
  for (int i = base + t; i < end; i += 256){
    int b = idx[i];
    int p = atomicAdd(&lcur[b], 1);
    outl[lbase[b] + p] = i;
  }
}

// ---------------- operand set for one 16-edge tile (CSR order), packed at load ----------------
// atoms+rbf bf16-packed at load (verified absmax 0.0156); edge feats f32 (round-4's bf16
// edge pack cost 19%). ~36 VGPRs live per copy once packed.
struct TileRegs {
  bfrag a0, a1, a2, a3;    // atom_i[0:32], atom_i[32:64], atom_j[0:32], atom_j[32:64] bf16
  bfrag rf;                // rbf (zero-padded) bf16
  float4 re0, re1, re2, re3;  // edge feats f32 (multiply MFMA output)
};

__device__ __forceinline__ TileRegs load_tile(const float* __restrict__ atom, const float* __restrict__ edgef,
                                              const float* __restrict__ rbff, const int4* __restrict__ edat,
                                              size_t r0, int e16, int g, int E){
  TileRegs R;
  size_t er = r0 + e16;
  if (er >= (size_t)E) er = 0;
  const int4 ed = edat[er];
  const float4* Ai = (const float4*)(atom + (size_t)ed.x*64);
  const float4* Aj = (const float4*)(atom + (size_t)ed.y*64);
  float4 ra0 = Ai[g*2],   ra1 = Ai[g*2+1];
  float4 rb0 = Ai[8+g*2], rb1 = Ai[8+g*2+1];
  float4 rc0 = Aj[g*2],   rc1 = Aj[g*2+1];
  float4 rd0 = Aj[8+g*2], rd1 = Aj[8+g*2+1];
  float4 rr0 = make_float4(0.f,0.f,0.f,0.f);
  float4 rr1 = make_float4(0.f,0.f,0.f,0.f);
  if (g < 2){
    const float4* rp = (const float4*)(rbff + (size_t)ed.z*16 + g*8);
    rr0 = rp[0]; rr1 = rp[1];
  }
  const float4* ep = (const float4*)(edgef + (size_t)ed.z*64);
  R.re0 = ep[g]; R.re1 = ep[4+g]; R.re2 = ep[8+g]; R.re3 = ep[12+g];
  R.a0 = pack8(ra0, ra1);
  R.a1 = pack8(rb0, rb1);
  R.a2 = pack8(rc0, rc1);
  R.a3 = pack8(rd0, rd1);
  R.rf = pack8(rr0, rr1);
  return R;
}

// ---------------- edge GEMM: depth-1 + sched_barrier prefetch pin, NO LDS ----------------
// Round-8 result: sched_barrier(0) after the prefetch+pack forced short raw-load live
// ranges -> VGPR 188->76 (the 65-128 / 4-waves-per-SIMD class), occupancy 11->31%,
// dur 297->261us. The binding constraint is now the 48KB LDS-B (3 blocks/CU = 12
// waves/CU; VGPR would allow 16). Round 3 proved B-from-L2 == B-from-LDS at equal
// occupancy, so this round drops LDS entirely: 4 blocks/CU -> 16 waves/CU. Bpack (48KB)
// is L2-resident; aggregate B-read ~15 TB/s < 34.5 TB/s L2 ceiling at 4 blocks/CU.
// Tripwires: VGPR must stay <=128; FETCH ~380MB (no spill).
template<int FNT0, int FNT1>
__global__ __launch_bounds__(256) void k_gemm(const float* __restrict__ atom, const float* __restrict__ edgef,
                                              const float* __restrict__ rbff, const int4* __restrict__ edat,
                                              const float* __restrict__ Wrbf,
                                              const unsigned short* __restrict__ Bpack,
                                              unsigned short* __restrict__ gated, int gstride, int colOff,
                                              int nT, int E)
{
  const int lane = threadIdx.x & 63;
  const int wid  = (blockIdx.x*256 + threadIdx.x) >> 6;
  const int nW   = gridDim.x*4;
  const int e16  = lane & 15;
  const int g    = lane >> 4;
  const f4 zero = {0.f, 0.f, 0.f, 0.f};

  bfrag wf[4];
#pragma unroll
  for (int ct = 0; ct < 4; ++ct){
#pragma unroll
    for (int i = 0; i < 8; ++i){
      float v = (g < 2) ? Wrbf[(g*8 + i)*64 + ct*16 + e16] : 0.f;
      wf[ct][i] = (short)f2bf(v);
    }
  }

  size_t t = (size_t)wid;
  if (t >= (size_t)nT) return;
  TileRegs cur = load_tile(atom, edgef, rbff, edat, t*16, e16, g, E);

  while (true){
    const size_t tn = t + (size_t)nW;
    const bool more = tn < (size_t)nT;
    TileRegs nxt;
    if (more) nxt = load_tile(atom, edgef, rbff, edat, tn*16, e16, g, E);
    // Pin: the t+1 prefetch loads + packs must issue before the compute below.
    __builtin_amdgcn_sched_barrier(0);

    const size_t r0 = t*16;
    size_t er = r0 + e16;
    const bool rowOK = er < (size_t)E;
    if (!rowOK) er = 0;

    f4 h0 = __builtin_amdgcn_mfma_f32_16x16x32_bf16(wf[0], cur.rf, zero, 0, 0, 0);
    f4 h1 = __builtin_amdgcn_mfma_f32_16x16x32_bf16(wf[1], cur.rf, zero, 0, 0, 0);
    f4 h2 = __builtin_amdgcn_mfma_f32_16x16x32_bf16(wf[2], cur.rf, zero, 0, 0, 0);
    f4 h3 = __builtin_amdgcn_mfma_f32_16x16x32_bf16(wf[3], cur.rf, zero, 0, 0, 0);

    bfrag aops[6];
    aops[0] = cur.a0; aops[1] = cur.a1; aops[2] = cur.a2; aops[3] = cur.a3;
    const float* pe0 = (const float*)&cur.re0;
    const float* pe1 = (const float*)&cur.re1;
    const float* pe2 = (const float*)&cur.re2;
    const float* pe3 = (const float*)&cur.re3;
#pragma unroll
    for (int r = 0; r < 4; ++r){
      aops[4][r]   = (short)f2bf(h0[r]*pe0[r]);
      aops[4][4+r] = (short)f2bf(h1[r]*pe1[r]);
      aops[5][r]   = (short)f2bf(h2[r]*pe2[r]);
      aops[5][4+r] = (short)f2bf(h3[r]*pe3[r]);
    }

    unsigned short* orow = gated + er*(size_t)gstride - colOff;
#pragma unroll
    for (int f_nt = FNT0; f_nt < FNT1; ++f_nt){
      const unsigned short* bb = Bpack + ((size_t)(f_nt*64 + lane))*8;
      f4 acc = zero;
#pragma unroll
      for (int ks = 0; ks < 6; ++ks){
        bfrag b = *(const bfrag*)(bb + (size_t)ks*4096);
        acc = __builtin_amdgcn_mfma_f32_16x16x32_bf16(b, aops[ks], acc, 0, 0, 0);   // D[col][edge]
      }
      if (rowOK){
        uint2 pk;
        pk.x = pk2bf(acc[0], acc[1]);
        pk.y = pk2bf(acc[2], acc[3]);
        *(uint2*)(orow + f_nt*16 + g*4) = pk;
      }
    }

    if (!more) break;
    cur = nxt;
    t = tn;
  }
}

// ---------------- crystal stats, sorted segmented reduce, full 128-col rows ----------------
__global__ __launch_bounds__(256) void k_cstats128(const unsigned short* __restrict__ gated,
                                                   const int* __restrict__ coffs, const int* __restrict__ celist,
                                                   float* __restrict__ pstat){
  int cr = blockIdx.x >> 3, s = blockIdx.x & 7;
  int t = threadIdx.x, w = t >> 6, lane = t & 63;
  int o0 = coffs[cr], o1 = coffs[cr+1];
  long long L = o1 - o0;
  int lo = o0 + (int)(L*s/8), hi = o0 + (int)(L*(s+1)/8);
  float S0=0.f, Q0=0.f, S1=0.f, Q1=0.f;
  for (int p = lo + w*8; p < hi; p += 32){
#pragma unroll
    for (int u = 0; u < 8; ++u){
      if (p + u < hi){
        int e = celist[p+u];
        unsigned v = *(const unsigned*)(gated + (size_t)e*128 + lane*2);
        float a = bf2f((unsigned short)(v & 0xffffu));
        float b = bf2f((unsigned short)(v >> 16));
        S0 += a; Q0 += a*a; S1 += b; Q1 += b*b;
      }
    }
  }
  __shared__ float sP[4][256];
  sP[w][lane*4+0]=S0; sP[w][lane*4+1]=Q0; sP[w][lane*4+2]=S1; sP[w][lane*4+3]=Q1;
  __syncthreads();
  float v = sP[0][t] + sP[1][t] + sP[2][t] + sP[3][t];
  pstat[((size_t)blockIdx.x << 8) + t] = v;
}

// 64-col bf16 variant (fallback half-rows)
__global__ __launch_bounds__(256) void k_cstats64(const unsigned short* __restrict__ gated,
                                                  const int* __restrict__ coffs, const int* __restrict__ celist,
                                                  float* __restrict__ pstat){
  int cr = blockIdx.x >> 3, s = blockIdx.x & 7;
  int t = threadIdx.x, w = t >> 6, lane = t & 63;
  int o0 = coffs[cr], o1 = coffs[cr+1];
  long long L = o1 - o0;
  int lo = o0 + (int)(L*s/8), hi = o0 + (int)(L*(s+1)/8);
  float S=0.f, Q=0.f;
  for (int p = lo + w*8; p < hi; p += 32){
#pragma unroll
    for (int u = 0; u < 8; ++u){
      if (p + u < hi){
        int e = celist[p+u];
        float a = bf2f(gated[(size_t)e*64 + lane]);
        S += a; Q += a*a;
      }
    }
  }
  __shared__ float sP[4][128];
  sP[w][lane*2+0]=S; sP[w][lane*2+1]=Q;
  __syncthreads();
  if (t < 128){
    float v = sP[0][t] + sP[1][t] + sP[2][t] + sP[3][t];
    pstat[((size_t)blockIdx.x << 7) + t] = v;
  }
}

// node stats: f32 rows / in-degree
__global__ __launch_bounds__(256) void k_cnstats(const float* __restrict__ nacc, const int* __restrict__ ncnt,
                                                 const int* __restrict__ coffs, const int* __restrict__ cnlist,
                                                 float* __restrict__ pstat){
  int cr = blockIdx.x >> 1, s = blockIdx.x & 1;
  int t = threadIdx.x, w = t >> 6, lane = t & 63;
  int o0 = coffs[cr], o1 = coffs[cr+1];
  long long L = o1 - o0;
  int lo = o0 + (int)(L*s/2), hi = o0 + (int)(L*(s+1)/2);
  float S=0.f, Q=0.f;
  for (int p = lo + w*4; p < hi; p += 16){
#pragma unroll
    for (int u = 0; u < 4; ++u){
      if (p + u < hi){
        int n = cnlist[p+u];
        float inv = 1.f / fmaxf((float)ncnt[n], 1.f);
        float a = nacc[(size_t)n*64 + lane]*inv;
        S += a; Q += a*a;
      }
    }
  }
  __shared__ float sP[4][128];
  sP[w][lane*2+0]=S; sP[w][lane*2+1]=Q;
  __syncthreads();
  if (t < 128){
    float v = sP[0][t] + sP[1][t] + sP[2][t] + sP[3][t];
    pstat[((size_t)blockIdx.x << 7) + t] = v;
  }
}

// ---------------- partial reduce -> scale/shift + fused filter precompute ----------------
__global__ __launch_bounds__(256) void k_red128f(const float* __restrict__ pstat, const int* __restrict__ ccnt,
                                                 const float* __restrict__ gamma, const float* __restrict__ beta,
                                                 const float* __restrict__ Wm,
                                                 float* __restrict__ sc, float* __restrict__ sh,
                                                 float* __restrict__ w2, float* __restrict__ fb){
  int idx = blockIdx.x*256 + threadIdx.x;   // 256 cr x 128 col
  int cr = idx >> 7, col = idx & 127;
  int vS = ((col >> 1) << 2) + ((col & 1) << 1);
  float S=0.f, Q=0.f;
  for (int s2 = 0; s2 < 8; ++s2){
    const float* b = pstat + ((size_t)(cr*8 + s2) << 8);
    S += b[vS]; Q += b[vS+1];
  }
  float cnt = fmaxf((float)ccnt[cr], 1.f);
  float mean = S/cnt;
  float var = fmaxf(Q/cnt - mean*mean, 0.f);
  float r = 1.f / sqrtf(var + 1e-5f);
  float g = r*gamma[col];
  float shv = beta[col] - mean*g;
  sc[cr*128 + col] = g;
  sh[cr*128 + col] = shv;

  __shared__ float red[256];
  float contrib = 0.f;
  if (col < 64){
    float wmv = Wm[col];
    w2[cr*64 + col] = g*wmv;
    contrib = shv*wmv;
  }
  red[threadIdx.x] = contrib;
  __syncthreads();
  int lc = threadIdx.x & 127;
  for (int d = 32; d > 0; d >>= 1){
    if (lc < d) red[threadIdx.x] += red[threadIdx.x + d];
    __syncthreads();
  }
  if (lc == 0) fb[cr] = red[threadIdx.x];
}

__global__ __launch_bounds__(256) void k_red64(const float* __restrict__ pstat, int nsplit,
                                               const int* __restrict__ ccnt,
                                               const float* __restrict__ gamma, const float* __restrict__ beta,
                                               float* __restrict__ sc, float* __restrict__ sh,
                                               int stride, int colOff){
  int idx = blockIdx.x*256 + threadIdx.x;   // 256 cr x 64 col
  int cr = idx >> 6, col = idx & 63;
  int vS = col*2;
  float S=0.f, Q=0.f;
  for (int s2 = 0; s2 < nsplit; ++s2){
    const float* b = pstat + ((size_t)(cr*nsplit + s2) << 7);
    S += b[vS]; Q += b[vS+1];
  }
  float cnt = fmaxf((float)ccnt[cr], 1.f);
  float mean = S/cnt;
  float var = fmaxf(Q/cnt - mean*mean, 0.f);
  float r = 1.f / sqrtf(var + 1e-5f);
  float g = r*gamma[col];
  sc[cr*stride + colOff + col] = g;
  sh[cr*stride + colOff + col] = beta[col] - mean*g;
}

// ---------------- filter precompute (fallback path only) ----------------
__global__ __launch_bounds__(256) void k_fprep(const float* __restrict__ scE, const float* __restrict__ shE,
                                               const float* __restrict__ Wm, float* __restrict__ w2,
                                               float* __restrict__ fb){
  int t = threadIdx.x, w = t >> 6, lane = t & 63;
  int cr = blockIdx.x*4 + w;
  float wm = Wm[lane];
  w2[cr*64 + lane] = scE[cr*128 + lane]*wm;
  float b = shE[cr*128 + lane]*wm;
#pragma unroll
  for (int d = 1; d < 64; d <<= 1) b += __shfl_xor(b, d, 64);
  if (lane == 0) fb[cr] = b;
}

// ---------------- fallback standalone filter ----------------
__global__ __launch_bounds__(256) void k_filter(const unsigned short* __restrict__ gated, int gst,
                                                const int4* __restrict__ edat, const float* __restrict__ w2,
                                                const float* __restrict__ fb, float* __restrict__ filt, int E){
  size_t r = (size_t)blockIdx.x*256 + threadIdx.x;
  if (r >= (size_t)E) return;
  int cr = edat[r].w;
  const uint4* row = (const uint4*)(gated + r*(size_t)gst);
  const float4* wr = (const float4*)(w2 + cr*64);
  float logit = fb[cr];
#pragma unroll
  for (int j = 0; j < 8; ++j){
    uint4 v = row[j];
    float4 wa = wr[2*j], wb = wr[2*j+1];
    logit += bf2f((unsigned short)(v.x & 0xffffu))*wa.x + bf2f((unsigned short)(v.x >> 16))*wa.y;
    logit += bf2f((unsigned short)(v.y & 0xffffu))*wa.z + bf2f((unsigned short)(v.y >> 16))*wa.w;
    logit += bf2f((unsigned short)(v.z & 0xffffu))*wb.x + bf2f((unsigned short)(v.z >> 16))*wb.y;
    logit += bf2f((unsigned short)(v.w & 0xffffu))*wb.z + bf2f((unsigned short)(v.w >> 16))*wb.w;
  }
  filt[r] = 1.f / (1.f + __expf(-logit));
}

// ---------------- FUSED filter + message gather: 8 lanes/edge, 8 edges/iter ----------------
// group sub = lane>>3 handles edge p+sub; c8 = lane&7 covers cols 8*c8..8*c8+7.
__global__ __launch_bounds__(256) void k_msgf8(const unsigned short* __restrict__ gated,
                                               const int4* __restrict__ edat,
                                               const int* __restrict__ offs,
                                               const float* __restrict__ scE, const float* __restrict__ shE,
                                               const float* __restrict__ w2, const float* __restrict__ fb,
                                               float* __restrict__ nacc, int NN){
  int w = threadIdx.x >> 6, lane = threadIdx.x & 63;
  int n = blockIdx.x*4 + w;
  if (n >= NN) return;
  int sub = lane >> 3, c8 = lane & 7;
  float a0=0.f,a1=0.f,a2=0.f,a3=0.f,a4=0.f,a5=0.f,a6=0.f,a7=0.f;
  int p0 = offs[n], p1 = offs[n+1];
  for (int p = p0; p < p1; p += 8){
    int q = p + sub;
    bool ok = q < p1;
    if (!ok) q = p;
    int cr = edat[q].w;
    // filter part: cols 8*c8 .. 8*c8+7
    uint4 vf = *(const uint4*)(gated + (size_t)q*128 + c8*8);
    const float4* wvp = (const float4*)(w2 + cr*64 + c8*8);
    float4 wv0 = wvp[0], wv1 = wvp[1];
    float part = bf2f((unsigned short)(vf.x & 0xffffu))*wv0.x
               + bf2f((unsigned short)(vf.x >> 16))*wv0.y
               + bf2f((unsigned short)(vf.y & 0xffffu))*wv0.z
               + bf2f((unsigned short)(vf.y >> 16))*wv0.w
               + bf2f((unsigned short)(vf.z & 0xffffu))*wv1.x
               + bf2f((unsigned short)(vf.z >> 16))*wv1.y
               + bf2f((unsigned short)(vf.w & 0xffffu))*wv1.z
               + bf2f((unsigned short)(vf.w >> 16))*wv1.w;
#pragma unroll
    for (int d = 1; d < 8; d <<= 1) part += __shfl_xor(part, d, 64);  // within 8-lane group
    float f = 1.f / (1.f + __expf(-(part + fb[cr])));
    // core part: cols 64 + 8*c8 .. 64 + 8*c8+7
    uint4 vc = *(const uint4*)(gated + (size_t)q*128 + 64 + c8*8);
    const float4* scp = (const float4*)(scE + cr*128 + 64 + c8*8);
    const float4* shp = (const float4*)(shE + cr*128 + 64 + c8*8);
    float4 s0 = scp[0], s1 = scp[1];
    float4 h0 = shp[0], h1 = shp[1];
    if (ok){
      a0 += f*fmaxf(bf2f((unsigned short)(vc.x & 0xffffu))*s0.x + h0.x, 0.f);
      a1 += f*fmaxf(bf2f((unsigned short)(vc.x >> 16))*s0.y + h0.y, 0.f);
      a2 += f*fmaxf(bf2f((unsigned short)(vc.y & 0xffffu))*s0.z + h0.z, 0.f);
      a3 += f*fmaxf(bf2f((unsigned short)(vc.y >> 16))*s0.w + h0.w, 0.f);
      a4 += f*fmaxf(bf2f((unsigned short)(vc.z & 0xffffu))*s1.x + h1.x, 0.f);
      a5 += f*fmaxf(bf2f((unsigned short)(vc.z >> 16))*s1.y + h1.y, 0.f);
      a6 += f*fmaxf(bf2f((unsigned short)(vc.w & 0xffffu))*s1.z + h1.z, 0.f);
      a7 += f*fmaxf(bf2f((unsigned short)(vc.w >> 16))*s1.w + h1.w, 0.f);
    }
  }
#pragma unroll
  for (int d = 8; d < 64; d <<= 1){
    a0 += __shfl_xor(a0, d, 64); a1 += __shfl_xor(a1, d, 64);
    a2 += __shfl_xor(a2, d, 64); a3 += __shfl_xor(a3, d, 64);
    a4 += __shfl_xor(a4, d, 64); a5 += __shfl_xor(a5, d, 64);
    a6 += __shfl_xor(a6, d, 64); a7 += __shfl_xor(a7, d, 64);
  }
  if (lane < 8){
    float4 o0; o0.x = a0; o0.y = a1; o0.z = a2; o0.w = a3;
    float4 o1; o1.x = a4; o1.y = a5; o1.z = a6; o1.w = a7;
    float4* dst = (float4*)(nacc + (size_t)n*64 + (size_t)c8*8);
    dst[0] = o0; dst[1] = o1;
  }
}

// ---------------- fallback msg (separate halves + filt buffer) ----------------
__global__ __launch_bounds__(256) void k_msg3(const unsigned short* __restrict__ gated, int gst, int colBase,
                                              const int4* __restrict__ edat, const float* __restrict__ filt,
                                              const int* __restrict__ offs,
                                              const float* __restrict__ scE, const float* __restrict__ shE,
                                              int scOff, float* __restrict__ nacc, int NN){
  int w = threadIdx.x >> 6, lane = threadIdx.x & 63;
  int n = blockIdx.x*4 + w;
  if (n >= NN) return;
  int sub = lane >> 5, c2 = lane & 31;
  float a0 = 0.f, a1 = 0.f;
  int p0 = offs[n], p1 = offs[n+1];
  for (int p = p0; p < p1; p += 2){
    int idx = p + sub;
    bool ok = idx < p1;
    int q = ok ? idx : p;
    unsigned v = *(const unsigned*)(gated + (size_t)q*gst + colBase + c2*2);
    float f = filt[q];
    int cr = edat[q].w;
    float2 sc2 = *(const float2*)(scE + cr*128 + scOff + c2*2);
    float2 sh2 = *(const float2*)(shE + cr*128 + scOff + c2*2);
    if (ok){
      float g0 = bf2f((unsigned short)(v & 0xffffu));
      float g1 = bf2f((unsigned short)(v >> 16));
      a0 += f*fmaxf(g0*sc2.x + sh2.x, 0.f);
      a1 += f*fmaxf(g1*sc2.y + sh2.y, 0.f);
    }
  }
  a0 += __shfl_xor(a0, 32, 64);
  a1 += __shfl_xor(a1, 32, 64);
  if (lane < 32) *(float2*)(nacc + (size_t)n*64 + (size_t)c2*2) = make_float2(a0, a1);
}

// ---------------- node epilogue: norm + 2x residual MLP + final relu ----------------
__global__ __launch_bounds__(256) void k_final(const float* __restrict__ nacc, const int* __restrict__ ncnt,
                                               const int* __restrict__ cidx, const float* __restrict__ nsc,
                                               const float* __restrict__ nsh, const float* __restrict__ W1a,
                                               const float* __restrict__ W1b, const float* __restrict__ W2a,
                                               const float* __restrict__ W2b, const float* __restrict__ atom,
                                               float* __restrict__ out, int NN)
{
  __shared__ float sW[4][2048];
  __shared__ float hbuf[8192];
  int tid = threadIdx.x;
  for (int i = tid; i < 2048; i += 256){
    sW[0][i] = W1a[i]; sW[1][i] = W1b[i]; sW[2][i] = W2a[i]; sW[3][i] = W2b[i];
  }
  __syncthreads();
  int n = blockIdx.x*256 + tid;
  if (n >= NN) return;
  const float ISQ2 = 0.70710678118654752440f;
  int cr = cidx[n];
  float inv = 1.f / fmaxf((float)ncnt[n], 1.f);
  float x[64];
  const float4* src = (const float4*)(nacc + (size_t)n*64);
#pragma unroll
  for (int j = 0; j < 16; ++j){
    float4 v = src[j];
    x[4*j] = v.x*inv; x[4*j+1] = v.y*inv; x[4*j+2] = v.z*inv; x[4*j+3] = v.w*inv;
  }
#pragma unroll
  for (int c = 0; c < 64; ++c)
    x[c] = x[c]*nsc[cr*64 + c] + nsh[cr*64 + c];

  for (int blk = 0; blk < 2; ++blk){
    const float* sa = sW[blk*2];
    const float* sb = sW[blk*2 + 1];
    for (int j = 0; j < 32; ++j){
      float s = 0.f;
#pragma unroll
      for (int k = 0; k < 64; ++k) s += x[k]*sa[k*32 + j];
      hbuf[tid*32 + (j ^ (tid & 31))] = fmaxf(s, 0.f);
    }
    float x2[64];
#pragma unroll
    for (int c = 0; c < 64; ++c) x2[c] = 0.f;
    for (int j = 0; j < 32; ++j){
      float hj = hbuf[tid*32 + (j ^ (tid & 31))];
#pragma unroll
      for (int c = 0; c < 64; ++c) x2[c] += hj*sb[j*64 + c];
    }
#pragma unroll
    for (int c = 0; c < 64; ++c)
      x[c] = (x[c] + fmaxf(x2[c], 0.f))*ISQ2;
  }
  const float4* ap = (const float4*)(atom + (size_t)n*64);
  float4* op = (float4*)(out + (size_t)n*64);
#pragma unroll
  for (int j = 0; j < 16; ++j){
    float4 av = ap[j]; float4 o;
    o.x = ISQ2*fmaxf(av.x + x[4*j],   0.f);
    o.y = ISQ2*fmaxf(av.y + x[4*j+1], 0.f);
    o.z = ISQ2*fmaxf(av.z + x[4*j+2], 0.f);
    o.w = ISQ2*fmaxf(av.w + x[4*j+3], 0.f);
    op[j] = o;
  }
}

extern "C" void kernel_launch(void* const* d_in, const int* in_sizes, int n_in,
                              void* d_out, int out_size, void* d_ws, size_t ws_size,
                              hipStream_t stream)
{
  const float* atom  = (const float*)d_in[0];
  const float* edgef = (const float*)d_in[1];
  const float* rbff  = (const float*)d_in[2];
  const int*   nbr   = (const int*)d_in[3];
  const int*   cidxn = (const int*)d_in[4];
  const int*   cidxe = (const int*)d_in[5];
  const float* Wrbf  = (const float*)d_in[6];
  const float* Wful  = (const float*)d_in[7];
  const float* Wmask = (const float*)d_in[8];
  const float* g1    = (const float*)d_in[9];
  const float* b1    = (const float*)d_in[10];
  const float* g2    = (const float*)d_in[11];
  const float* b2    = (const float*)d_in[12];
  const float* W1a   = (const float*)d_in[13];
  const float* W1b   = (const float*)d_in[14];
  const float* W2a   = (const float*)d_in[15];
  const float* W2b   = (const float*)d_in[16];
  float* out = (float*)d_out;

  const int E  = in_sizes[1] / 64;
  const int NN = in_sizes[0] / 64;
  const int nT = (E + 15) / 16;

  char* p = (char*)d_ws;
  auto take = [&](size_t bytes){ void* r = (void*)p; p += (bytes + 255) & ~(size_t)255; return r; };

  const bool full = ws_size >= (size_t)360000000;
  const int gstride = full ? 128 : 64;

  unsigned short* gated = (unsigned short*)take((size_t)E*gstride*2);
  float* pstat  = (float*)take((size_t)2048*256*4);
  float* pstatN = (float*)take((size_t)512*128*4);
  float* nacc   = (float*)take((size_t)NN*64*4);
  int*   ncnt   = (int*)take((size_t)NN*4);
  int*   offs   = (int*)take((size_t)(NN+1)*4);
  int*   cursor = (int*)take((size_t)NN*4);
  int4*  edat   = (int4*)take((size_t)E*16);
  int*   celist = (int*)take((size_t)E*4);
  int*   cnlist = (int*)take((size_t)NN*4);
  int*   ceoffs = (int*)take(257*4);
  int*   cecur  = (int*)take(256*4);
  int*   cnoffs = (int*)take(257*4);
  int*   cncur  = (int*)take(256*4);
  int*   ccnte  = (int*)take(1024);
  int*   ccntn  = (int*)take(1024);
  float* scE    = (float*)take(256*128*4);
  float* shE    = (float*)take(256*128*4);
  float* nsc    = (float*)take(256*64*4);
  float* nsh    = (float*)take(256*64*4);
  float* w2     = (float*)take(256*64*4);
  float* fb     = (float*)take(256*4);
  float* filt   = (float*)take((size_t)E*4);
  unsigned short* Bpack = (unsigned short*)take(6*8*64*8*2);

  (void)hipMemsetAsync(ncnt,  0, (size_t)NN*4, stream);
  (void)hipMemsetAsync(ccnte, 0, 1024, stream);
  (void)hipMemsetAsync(ccntn, 0, 1024, stream);

  k_prep<<<48, 64, 0, stream>>>(Wful, Bpack);
  k_pre<<<2048, 256, 0, stream>>>(cidxe, E, cidxn, NN, nbr, ccnte, ccntn, ncnt);
  k_scans<<<3, 1024, 0, stream>>>(ncnt, NN, offs, cursor, ccnte, ccntn, ceoffs, cecur, cnoffs, cncur);
  k_scatter2<<<(E + 1023)/1024, 256, 0, stream>>>(nbr, cidxe, E, cursor, edat, cecur, celist);
  k_cscatter<<<(NN + 4095)/4096, 256, 0, stream>>>(cidxn, NN, cncur, cnlist);

  if (full){
    k_gemm<0,8><<<2048, 256, 0, stream>>>(atom, edgef, rbff, edat, Wrbf, Bpack, gated, 128, 0, nT, E);
    k_cstats128<<<2048, 256, 0, stream>>>(gated, ceoffs, celist, pstat);
    k_red128f<<<128, 256, 0, stream>>>(pstat, ccnte, g1, b1, Wmask, scE, shE, w2, fb);
    k_msgf8<<<(NN + 3)/4, 256, 0, stream>>>(gated, edat, offs, scE, shE, w2, fb, nacc, NN);
  } else {
    k_gemm<0,4><<<2048, 256, 0, stream>>>(atom, edgef, rbff, edat, Wrbf, Bpack, gated, 64, 0, nT, E);
    k_cstats64<<<2048, 256, 0, stream>>>(gated, ceoffs, celist, pstat);
    k_red64<<<64, 256, 0, stream>>>(pstat, 8, ccnte, g1, b1, scE, shE, 128, 0);
    k_fprep<<<64, 256, 0, stream>>>(scE, shE, Wmask, w2, fb);
    k_filter<<<(E + 255)/256, 256, 0, stream>>>(gated, 64, edat, w2, fb, filt, E);
    k_gemm<4,8><<<2048, 256, 0, stream>>>(atom, edgef, rbff, edat, Wrbf, Bpack, gated, 64, 64, nT, E);
    k_cstats64<<<2048, 256, 0, stream>>>(gated, ceoffs, celist, pstat);
    k_red64<<<64, 256, 0, stream>>>(pstat, 8, ccnte, g1 + 64, b1 + 64, scE, shE, 128, 64);
    k_msg3<<<(NN + 3)/4, 256, 0, stream>>>(gated, 64, 0, edat, filt, offs, scE, shE, 64, nacc, NN);
  }

  k_cnstats<<<512, 256, 0, stream>>>(nacc, ncnt, cnoffs, cnlist, pstatN);
  k_red64<<<64, 256, 0, stream>>>(pstatN, 2, ccntn, g2, b2, nsc, nsh, 64, 0);
  k_final<<<(NN + 255)/256, 256, 0, stream>>>(nacc, ncnt, cidxn, nsc, nsh, W1a, W1b, W2a, W2b, atom, out, NN);
}

// Round 10
// 920.133 us; speedup vs baseline: 1.0981x; 1.0981x over previous
//
#include <hip/hip_runtime.h>
#include <hip/hip_bf16.h>

typedef __attribute__((ext_vector_type(8))) short bfrag;
typedef __attribute__((ext_vector_type(4))) float f4;

__device__ __forceinline__ unsigned short f2bf(float f){
  unsigned b = __float_as_uint(f);
  b = (b + 0x7fffu + ((b >> 16) & 1u)) >> 16;
  return (unsigned short)b;
}
__device__ __forceinline__ unsigned pk2bf(float a, float b){
  return (unsigned)f2bf(a) | ((unsigned)f2bf(b) << 16);
}
__device__ __forceinline__ float bf2f(unsigned short u){
  return __uint_as_float(((unsigned)u) << 16);
}
__device__ __forceinline__ bfrag pack8(float4 x, float4 y){
  bfrag r;
  r[0]=(short)f2bf(x.x); r[1]=(short)f2bf(x.y); r[2]=(short)f2bf(x.z); r[3]=(short)f2bf(x.w);
  r[4]=(short)f2bf(y.x); r[5]=(short)f2bf(y.y); r[6]=(short)f2bf(y.z); r[7]=(short)f2bf(y.w);
  return r;
}

// ---------------- B pre-pack: W_full (192x128 f32) -> MFMA frag layout bf16 ----------------
__global__ __launch_bounds__(64) void k_prep(const float* __restrict__ Wf, unsigned short* __restrict__ Bpack){
  int l = threadIdx.x; int f = blockIdx.x; int ks = f >> 3; int nt = f & 7;
  int kg = l >> 4; int nn = l & 15;
#pragma unroll
  for (int j = 0; j < 8; ++j){
    int k;
    if (ks < 4) k = ks*32 + kg*8 + j;
    else        k = 128 + (ks-4)*32 + ((j>>2)<<4) + kg*4 + (j&3);
    Bpack[((size_t)f*64 + l)*8 + j] = f2bf(Wf[(size_t)k*128 + nt*16 + nn]);
  }
}

// ---------------- merged prepass: all three histograms in one launch ----------------
__global__ __launch_bounds__(256) void k_pre(const int* __restrict__ cidxe, int E,
                                             const int* __restrict__ cidxn, int NN,
                                             const int* __restrict__ nbr,
                                             int* __restrict__ ccnte, int* __restrict__ ccntn,
                                             int* __restrict__ ncnt){
  __shared__ int he[256], hn[256];
  int t = threadIdx.x;
  he[t] = 0; hn[t] = 0;
  __syncthreads();
  for (size_t i = (size_t)blockIdx.x*256 + t; i < (size_t)E; i += (size_t)gridDim.x*256){
    atomicAdd(&he[cidxe[i]], 1);
    atomicAdd(&ncnt[nbr[2*i]], 1);
  }
  for (size_t i = (size_t)blockIdx.x*256 + t; i < (size_t)NN; i += (size_t)gridDim.x*256)
    atomicAdd(&hn[cidxn[i]], 1);
  __syncthreads();
  if (he[t]) atomicAdd(&ccnte[t], he[t]);
  if (hn[t]) atomicAdd(&ccntn[t], hn[t]);
}

// ---------------- merged scans: block 0 = node-count scan (1024 thr); blocks 1,2 = 256-bin crystal scans ----------------
__global__ __launch_bounds__(1024) void k_scans(const int* __restrict__ ncnt, int NN,
                                                int* __restrict__ offs, int* __restrict__ cursor,
                                                const int* __restrict__ ccnte, const int* __restrict__ ccntn,
                                                int* __restrict__ ceoffs, int* __restrict__ cecur,
                                                int* __restrict__ cnoffs, int* __restrict__ cncur){
  int tid = threadIdx.x;
  if (blockIdx.x == 0){
    __shared__ int part[1024];
    int chunk = (NN + 1023) >> 10;
    int base = tid*chunk;
    int s = 0;
    for (int i = 0; i < chunk; ++i){ int p = base + i; if (p < NN) s += ncnt[p]; }
    part[tid] = s;
    __syncthreads();
    for (int d = 1; d < 1024; d <<= 1){
      int v = (tid >= d) ? part[tid - d] : 0;
      __syncthreads();
      part[tid] += v;
      __syncthreads();
    }
    int run = (tid == 0) ? 0 : part[tid-1];
    for (int i = 0; i < chunk; ++i){
      int p = base + i;
      if (p < NN){ offs[p] = run; cursor[p] = run; run += ncnt[p]; }
    }
    if (tid == 1023) offs[NN] = part[1023];
  } else {
    __shared__ int sh[256];
    const int* cnt = (blockIdx.x == 2) ? ccntn : ccnte;
    int* off = (blockIdx.x == 2) ? cnoffs : ceoffs;
    int* cur = (blockIdx.x == 2) ? cncur  : cecur;
    int v = 0;
    if (tid < 256){ v = cnt[tid]; sh[tid] = v; }
    __syncthreads();
    for (int d = 1; d < 256; d <<= 1){
      int x = (tid >= d && tid < 256) ? sh[tid - d] : 0;
      __syncthreads();
      if (tid < 256) sh[tid] += x;
      __syncthreads();
    }
    if (tid < 256){
      off[tid] = sh[tid] - v; cur[tid] = sh[tid] - v;
      if (tid == 255) off[256] = sh[255];
    }
  }
}

// ---------------- MERGED CSR scatter + crystal-list build ----------------
__global__ __launch_bounds__(256) void k_scatter2(const int* __restrict__ nbr, const int* __restrict__ cidxe,
                                                  int E, int* __restrict__ cursor, int4* __restrict__ edat,
                                                  int* __restrict__ gcur, int* __restrict__ celist){
  __shared__ int lhist[256], lbase[256], lcur[256];
  int t = threadIdx.x;
  lhist[t] = 0; lcur[t] = 0;
  __syncthreads();
  int base = blockIdx.x*1024;
  int end = min(base + 1024, E);
  for (int i = base + t; i < end; i += 256) atomicAdd(&lhist[cidxe[i]], 1);
  __syncthreads();
  if (lhist[t]) lbase[t] = atomicAdd(&gcur[t], lhist[t]);
  __syncthreads();
  for (int i = base + t; i < end; i += 256){
    int cr = cidxe[i];
    int n = nbr[2*(size_t)i];
    int j = nbr[2*(size_t)i + 1];
    int pos = atomicAdd(&cursor[n], 1);
    edat[pos] = make_int4(n, j, i, cr);
    int lp = atomicAdd(&lcur[cr], 1);
    celist[lbase[cr] + lp] = pos;
  }
}

// ---------------- hierarchical crystal scatter (node list) ----------------
__global__ __launch_bounds__(256) void k_cscatter(const int* __restrict__ idx, int n,
                                                  int* __restrict__ gcur, int* __restrict__ outl){
  __shared__ int lhist[256], lbase[256], lcur[256];
  int t = threadIdx.x;
  lhist[t] = 0; lcur[t] = 0;
  __syncthreads();
  int base = blockIdx.x*4096;
  int end = min(base + 4096, n);
  for (int i = base + t; i < end; i += 256) atomicAdd(&lhist[idx[i]], 1);
  __syncthreads();
  if (lhist[t]) lbase[t] = atomicAdd(&gcur[t], lhist[t]);
  __syncthreads();
  for (int i = base + t; i < end; i += 256){
    int b = idx[i];
    int p = atomicAdd(&lcur[b], 1);
    outl[lbase[b] + p] = i;
  }
}

// ---------------- operand set for one 16-edge tile (CSR order), packed at load ----------------
struct TileRegs {
  bfrag a0, a1, a2, a3;    // atom_i[0:32], atom_i[32:64], atom_j[0:32], atom_j[32:64] bf16
  bfrag rf;                // rbf (zero-padded) bf16
  float4 re0, re1, re2, re3;  // edge feats f32 (multiply MFMA output)
};

__device__ __forceinline__ TileRegs load_tile(const float* __restrict__ atom, const float* __restrict__ edgef,
                                              const float* __restrict__ rbff, const int4* __restrict__ edat,
                                              size_t r0, int e16, int g, int E){
  TileRegs R;
  size_t er = r0 + e16;
  if (er >= (size_t)E) er = 0;
  const int4 ed = edat[er];
  const float4* Ai = (const float4*)(atom + (size_t)ed.x*64);
  const float4* Aj = (const float4*)(atom + (size_t)ed.y*64);
  float4 ra0 = Ai[g*2],   ra1 = Ai[g*2+1];
  float4 rb0 = Ai[8+g*2], rb1 = Ai[8+g*2+1];
  float4 rc0 = Aj[g*2],   rc1 = Aj[g*2+1];
  float4 rd0 = Aj[8+g*2], rd1 = Aj[8+g*2+1];
  float4 rr0 = make_float4(0.f,0.f,0.f,0.f);
  float4 rr1 = make_float4(0.f,0.f,0.f,0.f);
  if (g < 2){
    const float4* rp = (const float4*)(rbff + (size_t)ed.z*16 + g*8);
    rr0 = rp[0]; rr1 = rp[1];
  }
  const float4* ep = (const float4*)(edgef + (size_t)ed.z*64);
  R.re0 = ep[g]; R.re1 = ep[4+g]; R.re2 = ep[8+g]; R.re3 = ep[12+g];
  R.a0 = pack8(ra0, ra1);
  R.a1 = pack8(rb0, rb1);
  R.a2 = pack8(rc0, rc1);
  R.a3 = pack8(rd0, rd1);
  R.rf = pack8(rr0, rr1);
  return R;
}

// ---------------- edge GEMM: 512-thread block, LDS-B + sched_barrier pin ----------------
// Round-8 (best, 261us): LDS-B + sched_barrier(0) -> VGPR 76 (65-128 class, 4 waves/SIMD),
// occ 31% = 12 waves/CU, capped by LDS (48KB -> 3 blocks x 4 waves). Round-9 (drop LDS):
// compiler hoisted B-loads, VGPR 172, occ 11%, 349us — LDS-B + pin is what HOLDS the
// low-VGPR class. This round keeps the round-8 combo and amortizes LDS with a 512-thread
// block: 2 blocks/CU x 8 waves = 16 waves/CU (the VGPR-class max), LDS 96KB <= 160KB.
// Tripwires: VGPR <= 128; FETCH ~380MB (no spill); LDS_Block_Size 49152.
template<int FNT0, int FNT1>
__global__ __launch_bounds__(512) void k_gemm(const float* __restrict__ atom, const float* __restrict__ edgef,
                                              const float* __restrict__ rbff, const int4* __restrict__ edat,
                                              const float* __restrict__ Wrbf,
                                              const unsigned short* __restrict__ Bpack,
                                              unsigned short* __restrict__ gated, int gstride, int colOff,
                                              int nT, int E)
{
  __shared__ uint4 sBv[3072];   // 48KB, 16B-aligned: [ks][f_nt][lane][8] bf16
  const unsigned short* sB = (const unsigned short*)sBv;
  const int lane = threadIdx.x & 63;
  const int wid  = (blockIdx.x*512 + threadIdx.x) >> 6;
  const int nW   = gridDim.x*8;
  const int e16  = lane & 15;
  const int g    = lane >> 4;
  const f4 zero = {0.f, 0.f, 0.f, 0.f};

  {
    const uint4* src = (const uint4*)Bpack;
    for (int i = threadIdx.x; i < 3072; i += 512) sBv[i] = src[i];
  }

  bfrag wf[4];
#pragma unroll
  for (int ct = 0; ct < 4; ++ct){
#pragma unroll
    for (int i = 0; i < 8; ++i){
      float v = (g < 2) ? Wrbf[(g*8 + i)*64 + ct*16 + e16] : 0.f;
      wf[ct][i] = (short)f2bf(v);
    }
  }
  __syncthreads();

  size_t t = (size_t)wid;
  if (t >= (size_t)nT) return;
  TileRegs cur = load_tile(atom, edgef, rbff, edat, t*16, e16, g, E);

  while (true){
    const size_t tn = t + (size_t)nW;
    const bool more = tn < (size_t)nT;
    TileRegs nxt;
    if (more) nxt = load_tile(atom, edgef, rbff, edat, tn*16, e16, g, E);
    // Pin: the t+1 prefetch loads + packs must issue before the compute below.
    __builtin_amdgcn_sched_barrier(0);

    const size_t r0 = t*16;
    size_t er = r0 + e16;
    const bool rowOK = er < (size_t)E;
    if (!rowOK) er = 0;

    f4 h0 = __builtin_amdgcn_mfma_f32_16x16x32_bf16(wf[0], cur.rf, zero, 0, 0, 0);
    f4 h1 = __builtin_amdgcn_mfma_f32_16x16x32_bf16(wf[1], cur.rf, zero, 0, 0, 0);
    f4 h2 = __builtin_amdgcn_mfma_f32_16x16x32_bf16(wf[2], cur.rf, zero, 0, 0, 0);
    f4 h3 = __builtin_amdgcn_mfma_f32_16x16x32_bf16(wf[3], cur.rf, zero, 0, 0, 0);

    bfrag aops[6];
    aops[0] = cur.a0; aops[1] = cur.a1; aops[2] = cur.a2; aops[3] = cur.a3;
    const float* pe0 = (const float*)&cur.re0;
    const float* pe1 = (const float*)&cur.re1;
    const float* pe2 = (const float*)&cur.re2;
    const float* pe3 = (const float*)&cur.re3;
#pragma unroll
    for (int r = 0; r < 4; ++r){
      aops[4][r]   = (short)f2bf(h0[r]*pe0[r]);
      aops[4][4+r] = (short)f2bf(h1[r]*pe1[r]);
      aops[5][r]   = (short)f2bf(h2[r]*pe2[r]);
      aops[5][4+r] = (short)f2bf(h3[r]*pe3[r]);
    }

    unsigned short* orow = gated + er*(size_t)gstride - colOff;
#pragma unroll
    for (int f_nt = FNT0; f_nt < FNT1; ++f_nt){
      const unsigned short* bls = sB + ((size_t)(f_nt*64 + lane))*8;
      f4 acc = zero;
#pragma unroll
      for (int ks = 0; ks < 6; ++ks){
        bfrag b = *(const bfrag*)(bls + (size_t)ks*4096);
        acc = __builtin_amdgcn_mfma_f32_16x16x32_bf16(b, aops[ks], acc, 0, 0, 0);   // D[col][edge]
      }
      if (rowOK){
        uint2 pk;
        pk.x = pk2bf(acc[0], acc[1]);
        pk.y = pk2bf(acc[2], acc[3]);
        *(uint2*)(orow + f_nt*16 + g*4) = pk;
      }
    }

    if (!more) break;
    cur = nxt;
    t = tn;
  }
}

// ---------------- crystal stats, sorted segmented reduce, full 128-col rows ----------------
__global__ __launch_bounds__(256) void k_cstats128(const unsigned short* __restrict__ gated,
                                                   const int* __restrict__ coffs, const int* __restrict__ celist,
                                                   float* __restrict__ pstat){
  int cr = blockIdx.x >> 3, s = blockIdx.x & 7;
  int t = threadIdx.x, w = t >> 6, lane = t & 63;
  int o0 = coffs[cr], o1 = coffs[cr+1];
  long long L = o1 - o0;
  int lo = o0 + (int)(L*s/8), hi = o0 + (int)(L*(s+1)/8);
  float S0=0.f, Q0=0.f, S1=0.f, Q1=0.f;
  for (int p = lo + w*8; p < hi; p += 32){
#pragma unroll
    for (int u = 0; u < 8; ++u){
      if (p + u < hi){
        int e = celist[p+u];
        unsigned v = *(const unsigned*)(gated + (size_t)e*128 + lane*2);
        float a = bf2f((unsigned short)(v & 0xffffu));
        float b = bf2f((unsigned short)(v >> 16));
        S0 += a; Q0 += a*a; S1 += b; Q1 += b*b;
      }
    }
  }
  __shared__ float sP[4][256];
  sP[w][lane*4+0]=S0; sP[w][lane*4+1]=Q0; sP[w][lane*4+2]=S1; sP[w][lane*4+3]=Q1;
  __syncthreads();
  float v = sP[0][t] + sP[1][t] + sP[2][t] + sP[3][t];
  pstat[((size_t)blockIdx.x << 8) + t] = v;
}

// 64-col bf16 variant (fallback half-rows)
__global__ __launch_bounds__(256) void k_cstats64(const unsigned short* __restrict__ gated,
                                                  const int* __restrict__ coffs, const int* __restrict__ celist,
                                                  float* __restrict__ pstat){
  int cr = blockIdx.x >> 3, s = blockIdx.x & 7;
  int t = threadIdx.x, w = t >> 6, lane = t & 63;
  int o0 = coffs[cr], o1 = coffs[cr+1];
  long long L = o1 - o0;
  int lo = o0 + (int)(L*s/8), hi = o0 + (int)(L*(s+1)/8);
  float S=0.f, Q=0.f;
  for (int p = lo + w*8; p < hi; p += 32){
#pragma unroll
    for (int u = 0; u < 8; ++u){
      if (p + u < hi){
        int e = celist[p+u];
        float a = bf2f(gated[(size_t)e*64 + lane]);
        S += a; Q += a*a;
      }
    }
  }
  __shared__ float sP[4][128];
  sP[w][lane*2+0]=S; sP[w][lane*2+1]=Q;
  __syncthreads();
  if (t < 128){
    float v = sP[0][t] + sP[1][t] + sP[2][t] + sP[3][t];
    pstat[((size_t)blockIdx.x << 7) + t] = v;
  }
}

// node stats: f32 rows / in-degree
__global__ __launch_bounds__(256) void k_cnstats(const float* __restrict__ nacc, const int* __restrict__ ncnt,
                                                 const int* __restrict__ coffs, const int* __restrict__ cnlist,
                                                 float* __restrict__ pstat){
  int cr = blockIdx.x >> 1, s = blockIdx.x & 1;
  int t = threadIdx.x, w = t >> 6, lane = t & 63;
  int o0 = coffs[cr], o1 = coffs[cr+1];
  long long L = o1 - o0;
  int lo = o0 + (int)(L*s/2), hi = o0 + (int)(L*(s+1)/2);
  float S=0.f, Q=0.f;
  for (int p = lo + w*4; p < hi; p += 16){
#pragma unroll
    for (int u = 0; u < 4; ++u){
      if (p + u < hi){
        int n = cnlist[p+u];
        float inv = 1.f / fmaxf((float)ncnt[n], 1.f);
        float a = nacc[(size_t)n*64 + lane]*inv;
        S += a; Q += a*a;
      }
    }
  }
  __shared__ float sP[4][128];
  sP[w][lane*2+0]=S; sP[w][lane*2+1]=Q;
  __syncthreads();
  if (t < 128){
    float v = sP[0][t] + sP[1][t] + sP[2][t] + sP[3][t];
    pstat[((size_t)blockIdx.x << 7) + t] = v;
  }
}

// ---------------- partial reduce -> scale/shift + fused filter precompute ----------------
__global__ __launch_bounds__(256) void k_red128f(const float* __restrict__ pstat, const int* __restrict__ ccnt,
                                                 const float* __restrict__ gamma, const float* __restrict__ beta,
                                                 const float* __restrict__ Wm,
                                                 float* __restrict__ sc, float* __restrict__ sh,
                                                 float* __restrict__ w2, float* __restrict__ fb){
  int idx = blockIdx.x*256 + threadIdx.x;   // 256 cr x 128 col
  int cr = idx >> 7, col = idx & 127;
  int vS = ((col >> 1) << 2) + ((col & 1) << 1);
  float S=0.f, Q=0.f;
  for (int s2 = 0; s2 < 8; ++s2){
    const float* b = pstat + ((size_t)(cr*8 + s2) << 8);
    S += b[vS]; Q += b[vS+1];
  }
  float cnt = fmaxf((float)ccnt[cr], 1.f);
  float mean = S/cnt;
  float var = fmaxf(Q/cnt - mean*mean, 0.f);
  float r = 1.f / sqrtf(var + 1e-5f);
  float g = r*gamma[col];
  float shv = beta[col] - mean*g;
  sc[cr*128 + col] = g;
  sh[cr*128 + col] = shv;

  __shared__ float red[256];
  float contrib = 0.f;
  if (col < 64){
    float wmv = Wm[col];
    w2[cr*64 + col] = g*wmv;
    contrib = shv*wmv;
  }
  red[threadIdx.x] = contrib;
  __syncthreads();
  int lc = threadIdx.x & 127;
  for (int d = 32; d > 0; d >>= 1){
    if (lc < d) red[threadIdx.x] += red[threadIdx.x + d];
    __syncthreads();
  }
  if (lc == 0) fb[cr] = red[threadIdx.x];
}

__global__ __launch_bounds__(256) void k_red64(const float* __restrict__ pstat, int nsplit,
                                               const int* __restrict__ ccnt,
                                               const float* __restrict__ gamma, const float* __restrict__ beta,
                                               float* __restrict__ sc, float* __restrict__ sh,
                                               int stride, int colOff){
  int idx = blockIdx.x*256 + threadIdx.x;   // 256 cr x 64 col
  int cr = idx >> 6, col = idx & 63;
  int vS = col*2;
  float S=0.f, Q=0.f;
  for (int s2 = 0; s2 < nsplit; ++s2){
    const float* b = pstat + ((size_t)(cr*nsplit + s2) << 7);
    S += b[vS]; Q += b[vS+1];
  }
  float cnt = fmaxf((float)ccnt[cr], 1.f);
  float mean = S/cnt;
  float var = fmaxf(Q/cnt - mean*mean, 0.f);
  float r = 1.f / sqrtf(var + 1e-5f);
  float g = r*gamma[col];
  sc[cr*stride + colOff + col] = g;
  sh[cr*stride + colOff + col] = beta[col] - mean*g;
}

// ---------------- filter precompute (fallback path only) ----------------
__global__ __launch_bounds__(256) void k_fprep(const float* __restrict__ scE, const float* __restrict__ shE,
                                               const float* __restrict__ Wm, float* __restrict__ w2,
                                               float* __restrict__ fb){
  int t = threadIdx.x, w = t >> 6, lane = t & 63;
  int cr = blockIdx.x*4 + w;
  float wm = Wm[lane];
  w2[cr*64 + lane] = scE[cr*128 + lane]*wm;
  float b = shE[cr*128 + lane]*wm;
#pragma unroll
  for (int d = 1; d < 64; d <<= 1) b += __shfl_xor(b, d, 64);
  if (lane == 0) fb[cr] = b;
}

// ---------------- fallback standalone filter ----------------
__global__ __launch_bounds__(256) void k_filter(const unsigned short* __restrict__ gated, int gst,
                                                const int4* __restrict__ edat, const float* __restrict__ w2,
                                                const float* __restrict__ fb, float* __restrict__ filt, int E){
  size_t r = (size_t)blockIdx.x*256 + threadIdx.x;
  if (r >= (size_t)E) return;
  int cr = edat[r].w;
  const uint4* row = (const uint4*)(gated + r*(size_t)gst);
  const float4* wr = (const float4*)(w2 + cr*64);
  float logit = fb[cr];
#pragma unroll
  for (int j = 0; j < 8; ++j){
    uint4 v = row[j];
    float4 wa = wr[2*j], wb = wr[2*j+1];
    logit += bf2f((unsigned short)(v.x & 0xffffu))*wa.x + bf2f((unsigned short)(v.x >> 16))*wa.y;
    logit += bf2f((unsigned short)(v.y & 0xffffu))*wa.z + bf2f((unsigned short)(v.y >> 16))*wa.w;
    logit += bf2f((unsigned short)(v.z & 0xffffu))*wb.x + bf2f((unsigned short)(v.z >> 16))*wb.y;
    logit += bf2f((unsigned short)(v.w & 0xffffu))*wb.z + bf2f((unsigned short)(v.w >> 16))*wb.w;
  }
  filt[r] = 1.f / (1.f + __expf(-logit));
}

// ---------------- FUSED filter + message gather: 8 lanes/edge, 8 edges/iter ----------------
__global__ __launch_bounds__(256) void k_msgf8(const unsigned short* __restrict__ gated,
                                               const int4* __restrict__ edat,
                                               const int* __restrict__ offs,
                                               const float* __restrict__ scE, const float* __restrict__ shE,
                                               const float* __restrict__ w2, const float* __restrict__ fb,
                                               float* __restrict__ nacc, int NN){
  int w = threadIdx.x >> 6, lane = threadIdx.x & 63;
  int n = blockIdx.x*4 + w;
  if (n >= NN) return;
  int sub = lane >> 3, c8 = lane & 7;
  float a0=0.f,a1=0.f,a2=0.f,a3=0.f,a4=0.f,a5=0.f,a6=0.f,a7=0.f;
  int p0 = offs[n], p1 = offs[n+1];
  for (int p = p0; p < p1; p += 8){
    int q = p + sub;
    bool ok = q < p1;
    if (!ok) q = p;
    int cr = edat[q].w;
    // filter part: cols 8*c8 .. 8*c8+7
    uint4 vf = *(const uint4*)(gated + (size_t)q*128 + c8*8);
    const float4* wvp = (const float4*)(w2 + cr*64 + c8*8);
    float4 wv0 = wvp[0], wv1 = wvp[1];
    float part = bf2f((unsigned short)(vf.x & 0xffffu))*wv0.x
               + bf2f((unsigned short)(vf.x >> 16))*wv0.y
               + bf2f((unsigned short)(vf.y & 0xffffu))*wv0.z
               + bf2f((unsigned short)(vf.y >> 16))*wv0.w
               + bf2f((unsigned short)(vf.z & 0xffffu))*wv1.x
               + bf2f((unsigned short)(vf.z >> 16))*wv1.y
               + bf2f((unsigned short)(vf.w & 0xffffu))*wv1.z
               + bf2f((unsigned short)(vf.w >> 16))*wv1.w;
#pragma unroll
    for (int d = 1; d < 8; d <<= 1) part += __shfl_xor(part, d, 64);  // within 8-lane group
    float f = 1.f / (1.f + __expf(-(part + fb[cr])));
    // core part: cols 64 + 8*c8 .. 64 + 8*c8+7
    uint4 vc = *(const uint4*)(gated + (size_t)q*128 + 64 + c8*8);
    const float4* scp = (const float4*)(scE + cr*128 + 64 + c8*8);
    const float4* shp = (const float4*)(shE + cr*128 + 64 + c8*8);
    float4 s0 = scp[0], s1 = scp[1];
    float4 h0 = shp[0], h1 = shp[1];
    if (ok){
      a0 += f*fmaxf(bf2f((unsigned short)(vc.x & 0xffffu))*s0.x + h0.x, 0.f);
      a1 += f*fmaxf(bf2f((unsigned short)(vc.x >> 16))*s0.y + h0.y, 0.f);
      a2 += f*fmaxf(bf2f((unsigned short)(vc.y & 0xffffu))*s0.z + h0.z, 0.f);
      a3 += f*fmaxf(bf2f((unsigned short)(vc.y >> 16))*s0.w + h0.w, 0.f);
      a4 += f*fmaxf(bf2f((unsigned short)(vc.z & 0xffffu))*s1.x + h1.x, 0.f);
      a5 += f*fmaxf(bf2f((unsigned short)(vc.z >> 16))*s1.y + h1.y, 0.f);
      a6 += f*fmaxf(bf2f((unsigned short)(vc.w & 0xffffu))*s1.z + h1.z, 0.f);
      a7 += f*fmaxf(bf2f((unsigned short)(vc.w >> 16))*s1.w + h1.w, 0.f);
    }
  }
#pragma unroll
  for (int d = 8; d < 64; d <<= 1){
    a0 += __shfl_xor(a0, d, 64); a1 += __shfl_xor(a1, d, 64);
    a2 += __shfl_xor(a2, d, 64); a3 += __shfl_xor(a3, d, 64);
    a4 += __shfl_xor(a4, d, 64); a5 += __shfl_xor(a5, d, 64);
    a6 += __shfl_xor(a6, d, 64); a7 += __shfl_xor(a7, d, 64);
  }
  if (lane < 8){
    float4 o0; o0.x = a0; o0.y = a1; o0.z = a2; o0.w = a3;
    float4 o1; o1.x = a4; o1.y = a5; o1.z = a6; o1.w = a7;
    float4* dst = (float4*)(nacc + (size_t)n*64 + (size_t)c8*8);
    dst[0] = o0; dst[1] = o1;
  }
}

// ---------------- fallback msg (separate halves + filt buffer) ----------------
__global__ __launch_bounds__(256) void k_msg3(const unsigned short* __restrict__ gated, int gst, int colBase,
                                              const int4* __restrict__ edat, const float* __restrict__ filt,
                                              const int* __restrict__ offs,
                                              const float* __restrict__ scE, const float* __restrict__ shE,
                                              int scOff, float* __restrict__ nacc, int NN){
  int w = threadIdx.x >> 6, lane = threadIdx.x & 63;
  int n = blockIdx.x*4 + w;
  if (n >= NN) return;
  int sub = lane >> 5, c2 = lane & 31;
  float a0 = 0.f, a1 = 0.f;
  int p0 = offs[n], p1 = offs[n+1];
  for (int p = p0; p < p1; p += 2){
    int idx = p + sub;
    bool ok = idx < p1;
    int q = ok ? idx : p;
    unsigned v = *(const unsigned*)(gated + (size_t)q*gst + colBase + c2*2);
    float f = filt[q];
    int cr = edat[q].w;
    float2 sc2 = *(const float2*)(scE + cr*128 + scOff + c2*2);
    float2 sh2 = *(const float2*)(shE + cr*128 + scOff + c2*2);
    if (ok){
      float g0 = bf2f((unsigned short)(v & 0xffffu));
      float g1 = bf2f((unsigned short)(v >> 16));
      a0 += f*fmaxf(g0*sc2.x + sh2.x, 0.f);
      a1 += f*fmaxf(g1*sc2.y + sh2.y, 0.f);
    }
  }
  a0 += __shfl_xor(a0, 32, 64);
  a1 += __shfl_xor(a1, 32, 64);
  if (lane < 32) *(float2*)(nacc + (size_t)n*64 + (size_t)c2*2) = make_float2(a0, a1);
}

// ---------------- node epilogue: norm + 2x residual MLP + final relu ----------------
__global__ __launch_bounds__(256) void k_final(const float* __restrict__ nacc, const int* __restrict__ ncnt,
                                               const int* __restrict__ cidx, const float* __restrict__ nsc,
                                               const float* __restrict__ nsh, const float* __restrict__ W1a,
                                               const float* __restrict__ W1b, const float* __restrict__ W2a,
                                               const float* __restrict__ W2b, const float* __restrict__ atom,
                                               float* __restrict__ out, int NN)
{
  __shared__ float sW[4][2048];
  __shared__ float hbuf[8192];
  int tid = threadIdx.x;
  for (int i = tid; i < 2048; i += 256){
    sW[0][i] = W1a[i]; sW[1][i] = W1b[i]; sW[2][i] = W2a[i]; sW[3][i] = W2b[i];
  }
  __syncthreads();
  int n = blockIdx.x*256 + tid;
  if (n >= NN) return;
  const float ISQ2 = 0.70710678118654752440f;
  int cr = cidx[n];
  float inv = 1.f / fmaxf((float)ncnt[n], 1.f);
  float x[64];
  const float4* src = (const float4*)(nacc + (size_t)n*64);
#pragma unroll
  for (int j = 0; j < 16; ++j){
    float4 v = src[j];
    x[4*j] = v.x*inv; x[4*j+1] = v.y*inv; x[4*j+2] = v.z*inv; x[4*j+3] = v.w*inv;
  }
#pragma unroll
  for (int c = 0; c < 64; ++c)
    x[c] = x[c]*nsc[cr*64 + c] + nsh[cr*64 + c];

  for (int blk = 0; blk < 2; ++blk){
    const float* sa = sW[blk*2];
    const float* sb = sW[blk*2 + 1];
    for (int j = 0; j < 32; ++j){
      float s = 0.f;
#pragma unroll
      for (int k = 0; k < 64; ++k) s += x[k]*sa[k*32 + j];
      hbuf[tid*32 + (j ^ (tid & 31))] = fmaxf(s, 0.f);
    }
    float x2[64];
#pragma unroll
    for (int c = 0; c < 64; ++c) x2[c] = 0.f;
    for (int j = 0; j < 32; ++j){
      float hj = hbuf[tid*32 + (j ^ (tid & 31))];
#pragma unroll
      for (int c = 0; c < 64; ++c) x2[c] += hj*sb[j*64 + c];
    }
#pragma unroll
    for (int c = 0; c < 64; ++c)
      x[c] = (x[c] + fmaxf(x2[c], 0.f))*ISQ2;
  }
  const float4* ap = (const float4*)(atom + (size_t)n*64);
  float4* op = (float4*)(out + (size_t)n*64);
#pragma unroll
  for (int j = 0; j < 16; ++j){
    float4 av = ap[j]; float4 o;
    o.x = ISQ2*fmaxf(av.x + x[4*j],   0.f);
    o.y = ISQ2*fmaxf(av.y + x[4*j+1], 0.f);
    o.z = ISQ2*fmaxf(av.z + x[4*j+2], 0.f);
    o.w = ISQ2*fmaxf(av.w + x[4*j+3], 0.f);
    op[j] = o;
  }
}

extern "C" void kernel_launch(void* const* d_in, const int* in_sizes, int n_in,
                              void* d_out, int out_size, void* d_ws, size_t ws_size,
                              hipStream_t stream)
{
  const float* atom  = (const float*)d_in[0];
  const float* edgef = (const float*)d_in[1];
  const float* rbff  = (const float*)d_in[2];
  const int*   nbr   = (const int*)d_in[3];
  const int*   cidxn = (const int*)d_in[4];
  const int*   cidxe = (const int*)d_in[5];
  const float* Wrbf  = (const float*)d_in[6];
  const float* Wful  = (const float*)d_in[7];
  const float* Wmask = (const float*)d_in[8];
  const float* g1    = (const float*)d_in[9];
  const float* b1    = (const float*)d_in[10];
  const float* g2    = (const float*)d_in[11];
  const float* b2    = (const float*)d_in[12];
  const float* W1a   = (const float*)d_in[13];
  const float* W1b   = (const float*)d_in[14];
  const float* W2a   = (const float*)d_in[15];
  const float* W2b   = (const float*)d_in[16];
  float* out = (float*)d_out;

  const int E  = in_sizes[1] / 64;
  const int NN = in_sizes[0] / 64;
  const int nT = (E + 15) / 16;

  char* p = (char*)d_ws;
  auto take = [&](size_t bytes){ void* r = (void*)p; p += (bytes + 255) & ~(size_t)255; return r; };

  const bool full = ws_size >= (size_t)360000000;
  const int gstride = full ? 128 : 64;

  unsigned short* gated = (unsigned short*)take((size_t)E*gstride*2);
  float* pstat  = (float*)take((size_t)2048*256*4);
  float* pstatN = (float*)take((size_t)512*128*4);
  float* nacc   = (float*)take((size_t)NN*64*4);
  int*   ncnt   = (int*)take((size_t)NN*4);
  int*   offs   = (int*)take((size_t)(NN+1)*4);
  int*   cursor = (int*)take((size_t)NN*4);
  int4*  edat   = (int4*)take((size_t)E*16);
  int*   celist = (int*)take((size_t)E*4);
  int*   cnlist = (int*)take((size_t)NN*4);
  int*   ceoffs = (int*)take(257*4);
  int*   cecur  = (int*)take(256*4);
  int*   cnoffs = (int*)take(257*4);
  int*   cncur  = (int*)take(256*4);
  int*   ccnte  = (int*)take(1024);
  int*   ccntn  = (int*)take(1024);
  float* scE    = (float*)take(256*128*4);
  float* shE    = (float*)take(256*128*4);
  float* nsc    = (float*)take(256*64*4);
  float* nsh    = (float*)take(256*64*4);
  float* w2     = (float*)take(256*64*4);
  float* fb     = (float*)take(256*4);
  float* filt   = (float*)take((size_t)E*4);
  unsigned short* Bpack = (unsigned short*)take(6*8*64*8*2);

  (void)hipMemsetAsync(ncnt,  0, (size_t)NN*4, stream);
  (void)hipMemsetAsync(ccnte, 0, 1024, stream);
  (void)hipMemsetAsync(ccntn, 0, 1024, stream);

  k_prep<<<48, 64, 0, stream>>>(Wful, Bpack);
  k_pre<<<2048, 256, 0, stream>>>(cidxe, E, cidxn, NN, nbr, ccnte, ccntn, ncnt);
  k_scans<<<3, 1024, 0, stream>>>(ncnt, NN, offs, cursor, ccnte, ccntn, ceoffs, cecur, cnoffs, cncur);
  k_scatter2<<<(E + 1023)/1024, 256, 0, stream>>>(nbr, cidxe, E, cursor, edat, cecur, celist);
  k_cscatter<<<(NN + 4095)/4096, 256, 0, stream>>>(cidxn, NN, cncur, cnlist);

  if (full){
    k_gemm<0,8><<<1024, 512, 0, stream>>>(atom, edgef, rbff, edat, Wrbf, Bpack, gated, 128, 0, nT, E);
    k_cstats128<<<2048, 256, 0, stream>>>(gated, ceoffs, celist, pstat);
    k_red128f<<<128, 256, 0, stream>>>(pstat, ccnte, g1, b1, Wmask, scE, shE, w2, fb);
    k_msgf8<<<(NN + 3)/4, 256, 0, stream>>>(gated, edat, offs, scE, shE, w2, fb, nacc, NN);
  } else {
    k_gemm<0,4><<<1024, 512, 0, stream>>>(atom, edgef, rbff, edat, Wrbf, Bpack, gated, 64, 0, nT, E);
    k_cstats64<<<2048, 256, 0, stream>>>(gated, ceoffs, celist, pstat);
    k_red64<<<64, 256, 0, stream>>>(pstat, 8, ccnte, g1, b1, scE, shE, 128, 0);
    k_fprep<<<64, 256, 0, stream>>>(scE, shE, Wmask, w2, fb);
    k_filter<<<(E + 255)/256, 256, 0, stream>>>(gated, 64, edat, w2, fb, filt, E);
    k_gemm<4,8><<<1024, 512, 0, stream>>>(atom, edgef, rbff, edat, Wrbf, Bpack, gated, 64, 64, nT, E);
    k_cstats64<<<2048, 256, 0, stream>>>(gated, ceoffs, celist, pstat);
    k_red64<<<64, 256, 0, stream>>>(pstat, 8, ccnte, g1 + 64, b1 + 64, scE, shE, 128, 64);
    k_msg3<<<(NN + 3)/4, 256, 0, stream>>>(gated, 64, 0, edat, filt, offs, scE, shE, 64, nacc, NN);
  }

  k_cnstats<<<512, 256, 0, stream>>>(nacc, ncnt, cnoffs, cnlist, pstatN);
  k_red64<<<64, 256, 0, stream>>>(pstatN, 2, ccntn, g2, b2, nsc, nsh, 64, 0);
  k_final<<<(NN + 255)/256, 256, 0, stream>>>(nacc, ncnt, cidxn, nsc, nsh, W1a, W1b, W2a, W2b, atom, out, NN);
}

// Round 11
// 838.309 us; speedup vs baseline: 1.2053x; 1.0976x over previous
//
#include <hip/hip_runtime.h>
#include <hip/hip_bf16.h>

typedef __attribute__((ext_vector_type(8))) short bfrag;
typedef __attribute__((ext_vector_type(4))) float f4;

__device__ __forceinline__ unsigned short f2bf(float f){
  unsigned b = __float_as_uint(f);
  b = (b + 0x7fffu + ((b >> 16) & 1u)) >> 16;
  return (unsigned short)b;
}
__device__ __forceinline__ unsigned pk2bf(float a, float b){
  return (unsigned)f2bf(a) | ((unsigned)f2bf(b) << 16);
}
__device__ __forceinline__ float bf2f(unsigned short u){
  return __uint_as_float(((unsigned)u) << 16);
}
__device__ __forceinline__ bfrag pack8(float4 x, float4 y){
  bfrag r;
  r[0]=(short)f2bf(x.x); r[1]=(short)f2bf(x.y); r[2]=(short)f2bf(x.z); r[3]=(short)f2bf(x.w);
  r[4]=(short)f2bf(y.x); r[5]=(short)f2bf(y.y); r[6]=(short)f2bf(y.z); r[7]=(short)f2bf(y.w);
  return r;
}

// ---------------- B pre-pack: W_full (192x128 f32) -> MFMA frag layout bf16 ----------------
__global__ __launch_bounds__(64) void k_prep(const float* __restrict__ Wf, unsigned short* __restrict__ Bpack){
  int l = threadIdx.x; int f = blockIdx.x; int ks = f >> 3; int nt = f & 7;
  int kg = l >> 4; int nn = l & 15;
#pragma unroll
  for (int j = 0; j < 8; ++j){
    int k;
    if (ks < 4) k = ks*32 + kg*8 + j;
    else        k = 128 + (ks-4)*32 + ((j>>2)<<4) + kg*4 + (j&3);
    Bpack[((size_t)f*64 + l)*8 + j] = f2bf(Wf[(size_t)k*128 + nt*16 + nn]);
  }
}

// ---------------- merged prepass: all three histograms in one launch ----------------
__global__ __launch_bounds__(256) void k_pre(const int* __restrict__ cidxe, int E,
                                             const int* __restrict__ cidxn, int NN,
                                             const int* __restrict__ nbr,
                                             int* __restrict__ ccnte, int* __restrict__ ccntn,
                                             int* __restrict__ ncnt){
  __shared__ int he[256], hn[256];
  int t = threadIdx.x;
  he[t] = 0; hn[t] = 0;
  __syncthreads();
  for (size_t i = (size_t)blockIdx.x*256 + t; i < (size_t)E; i += (size_t)gridDim.x*256){
    atomicAdd(&he[cidxe[i]], 1);
    atomicAdd(&ncnt[nbr[2*i]], 1);
  }
  for (size_t i = (size_t)blockIdx.x*256 + t; i < (size_t)NN; i += (size_t)gridDim.x*256)
    atomicAdd(&hn[cidxn[i]], 1);
  __syncthreads();
  if (he[t]) atomicAdd(&ccnte[t], he[t]);
  if (hn[t]) atomicAdd(&ccntn[t], hn[t]);
}

// ---------------- merged scans: block 0 = node-count scan (1024 thr); blocks 1,2 = 256-bin crystal scans ----------------
__global__ __launch_bounds__(1024) void k_scans(const int* __restrict__ ncnt, int NN,
                                                int* __restrict__ offs, int* __restrict__ cursor,
                                                const int* __restrict__ ccnte, const int* __restrict__ ccntn,
                                                int* __restrict__ ceoffs, int* __restrict__ cecur,
                                                int* __restrict__ cnoffs, int* __restrict__ cncur){
  int tid = threadIdx.x;
  if (blockIdx.x == 0){
    __shared__ int part[1024];
    int chunk = (NN + 1023) >> 10;
    int base = tid*chunk;
    int s = 0;
    for (int i = 0; i < chunk; ++i){ int p = base + i; if (p < NN) s += ncnt[p]; }
    part[tid] = s;
    __syncthreads();
    for (int d = 1; d < 1024; d <<= 1){
      int v = (tid >= d) ? part[tid - d] : 0;
      __syncthreads();
      part[tid] += v;
      __syncthreads();
    }
    int run = (tid == 0) ? 0 : part[tid-1];
    for (int i = 0; i < chunk; ++i){
      int p = base + i;
      if (p < NN){ offs[p] = run; cursor[p] = run; run += ncnt[p]; }
    }
    if (tid == 1023) offs[NN] = part[1023];
  } else {
    __shared__ int sh[256];
    const int* cnt = (blockIdx.x == 2) ? ccntn : ccnte;
    int* off = (blockIdx.x == 2) ? cnoffs : ceoffs;
    int* cur = (blockIdx.x == 2) ? cncur  : cecur;
    int v = 0;
    if (tid < 256){ v = cnt[tid]; sh[tid] = v; }
    __syncthreads();
    for (int d = 1; d < 256; d <<= 1){
      int x = (tid >= d && tid < 256) ? sh[tid - d] : 0;
      __syncthreads();
      if (tid < 256) sh[tid] += x;
      __syncthreads();
    }
    if (tid < 256){
      off[tid] = sh[tid] - v; cur[tid] = sh[tid] - v;
      if (tid == 255) off[256] = sh[255];
    }
  }
}

// ---------------- MERGED CSR scatter + crystal-list build ----------------
__global__ __launch_bounds__(256) void k_scatter2(const int* __restrict__ nbr, const int* __restrict__ cidxe,
                                                  int E, int* __restrict__ cursor, int4* __restrict__ edat,
                                                  int* __restrict__ gcur, int* __restrict__ celist){
  __shared__ int lhist[256], lbase[256], lcur[256];
  int t = threadIdx.x;
  lhist[t] = 0; lcur[t] = 0;
  __syncthreads();
  int base = blockIdx.x*1024;
  int end = min(base + 1024, E);
  for (int i = base + t; i < end; i += 256) atomicAdd(&lhist[cidxe[i]], 1);
  __syncthreads();
  if (lhist[t]) lbase[t] = atomicAdd(&gcur[t], lhist[t]);
  __syncthreads();
  for (int i = base + t; i < end; i += 256){
    int cr = cidxe[i];
    int n = nbr[2*(size_t)i];
    int j = nbr[2*(size_t)i + 1];
    int pos = atomicAdd(&cursor[n], 1);
    edat[pos] = make_int4(n, j, i, cr);
    int lp = atomicAdd(&lcur[cr], 1);
    celist[lbase[cr] + lp] = pos;
  }
}

// ---------------- hierarchical crystal scatter (node list) ----------------
__global__ __launch_bounds__(256) void k_cscatter(const int* __restrict__ idx, int n,
                                                  int* __restrict__ gcur, int* __restrict__ outl){
  __shared__ int lhist[256], lbase[256], lcur[256];
  int t = threadIdx.x;
  lhist[t] = 0; lcur[t] = 0;
  __syncthreads();
  int base = blockIdx.x*4096;
  int end = min(base + 4096, n);
  for (int i = base + t; i < end; i += 256) atomicAdd(&lhist[idx[i]], 1);
  __syncthreads();
  if (lhist[t]) lbase[t] = atomicAdd(&gcur[t], lhist[t]);
  __syncthreads();
  for (int i = base + t; i < end; i += 256){
    int b = idx[i];
    int p = atomicAdd(&lcur[b], 1);
    outl[lbase[b] + p] = i;
  }
}

// ---------------- operand set for one 16-edge tile (CSR order), packed at load ----------------
struct TileRegs {
  bfrag a0, a1, a2, a3;    // atom_i[0:32], atom_i[32:64], atom_j[0:32], atom_j[32:64] bf16
  bfrag rf;                // rbf (zero-padded) bf16
  float4 re0, re1, re2, re3;  // edge feats f32 (multiply MFMA output)
};

__device__ __forceinline__ TileRegs load_tile(const float* __restrict__ atom, const float* __restrict__ edgef,
                                              const float* __restrict__ rbff, const int4* __restrict__ edat,
                                              size_t r0, int e16, int g, int E){
  TileRegs R;
  size_t er = r0 + e16;
  if (er >= (size_t)E) er = 0;
  const int4 ed = edat[er];
  const float4* Ai = (const float4*)(atom + (size_t)ed.x*64);
  const float4* Aj = (const float4*)(atom + (size_t)ed.y*64);
  float4 ra0 = Ai[g*2],   ra1 = Ai[g*2+1];
  float4 rb0 = Ai[8+g*2], rb1 = Ai[8+g*2+1];
  float4 rc0 = Aj[g*2],   rc1 = Aj[g*2+1];
  float4 rd0 = Aj[8+g*2], rd1 = Aj[8+g*2+1];
  float4 rr0 = make_float4(0.f,0.f,0.f,0.f);
  float4 rr1 = make_float4(0.f,0.f,0.f,0.f);
  if (g < 2){
    const float4* rp = (const float4*)(rbff + (size_t)ed.z*16 + g*8);
    rr0 = rp[0]; rr1 = rp[1];
  }
  const float4* ep = (const float4*)(edgef + (size_t)ed.z*64);
  R.re0 = ep[g]; R.re1 = ep[4+g]; R.re2 = ep[8+g]; R.re3 = ep[12+g];
  R.a0 = pack8(ra0, ra1);
  R.a1 = pack8(rb0, rb1);
  R.a2 = pack8(rc0, rc1);
  R.a3 = pack8(rd0, rd1);
  R.rf = pack8(rr0, rr1);
  return R;
}

// ---------------- edge GEMM: 512-thread block, LDS-B + sched_barrier pin (round-10 best) ----------------
template<int FNT0, int FNT1>
__global__ __launch_bounds__(512) void k_gemm(const float* __restrict__ atom, const float* __restrict__ edgef,
                                              const float* __restrict__ rbff, const int4* __restrict__ edat,
                                              const float* __restrict__ Wrbf,
                                              const unsigned short* __restrict__ Bpack,
                                              unsigned short* __restrict__ gated, int gstride, int colOff,
                                              int nT, int E)
{
  __shared__ uint4 sBv[3072];   // 48KB, 16B-aligned: [ks][f_nt][lane][8] bf16
  const unsigned short* sB = (const unsigned short*)sBv;
  const int lane = threadIdx.x & 63;
  const int wid  = (blockIdx.x*512 + threadIdx.x) >> 6;
  const int nW   = gridDim.x*8;
  const int e16  = lane & 15;
  const int g    = lane >> 4;
  const f4 zero = {0.f, 0.f, 0.f, 0.f};

  {
    const uint4* src = (const uint4*)Bpack;
    for (int i = threadIdx.x; i < 3072; i += 512) sBv[i] = src[i];
  }

  bfrag wf[4];
#pragma unroll
  for (int ct = 0; ct < 4; ++ct){
#pragma unroll
    for (int i = 0; i < 8; ++i){
      float v = (g < 2) ? Wrbf[(g*8 + i)*64 + ct*16 + e16] : 0.f;
      wf[ct][i] = (short)f2bf(v);
    }
  }
  __syncthreads();

  size_t t = (size_t)wid;
  if (t >= (size_t)nT) return;
  TileRegs cur = load_tile(atom, edgef, rbff, edat, t*16, e16, g, E);

  while (true){
    const size_t tn = t + (size_t)nW;
    const bool more = tn < (size_t)nT;
    TileRegs nxt;
    if (more) nxt = load_tile(atom, edgef, rbff, edat, tn*16, e16, g, E);
    // Pin: the t+1 prefetch loads + packs must issue before the compute below.
    __builtin_amdgcn_sched_barrier(0);

    const size_t r0 = t*16;
    size_t er = r0 + e16;
    const bool rowOK = er < (size_t)E;
    if (!rowOK) er = 0;

    f4 h0 = __builtin_amdgcn_mfma_f32_16x16x32_bf16(wf[0], cur.rf, zero, 0, 0, 0);
    f4 h1 = __builtin_amdgcn_mfma_f32_16x16x32_bf16(wf[1], cur.rf, zero, 0, 0, 0);
    f4 h2 = __builtin_amdgcn_mfma_f32_16x16x32_bf16(wf[2], cur.rf, zero, 0, 0, 0);
    f4 h3 = __builtin_amdgcn_mfma_f32_16x16x32_bf16(wf[3], cur.rf, zero, 0, 0, 0);

    bfrag aops[6];
    aops[0] = cur.a0; aops[1] = cur.a1; aops[2] = cur.a2; aops[3] = cur.a3;
    const float* pe0 = (const float*)&cur.re0;
    const float* pe1 = (const float*)&cur.re1;
    const float* pe2 = (const float*)&cur.re2;
    const float* pe3 = (const float*)&cur.re3;
#pragma unroll
    for (int r = 0; r < 4; ++r){
      aops[4][r]   = (short)f2bf(h0[r]*pe0[r]);
      aops[4][4+r] = (short)f2bf(h1[r]*pe1[r]);
      aops[5][r]   = (short)f2bf(h2[r]*pe2[r]);
      aops[5][4+r] = (short)f2bf(h3[r]*pe3[r]);
    }

    unsigned short* orow = gated + er*(size_t)gstride - colOff;
#pragma unroll
    for (int f_nt = FNT0; f_nt < FNT1; ++f_nt){
      const unsigned short* bls = sB + ((size_t)(f_nt*64 + lane))*8;
      f4 acc = zero;
#pragma unroll
      for (int ks = 0; ks < 6; ++ks){
        bfrag b = *(const bfrag*)(bls + (size_t)ks*4096);
        acc = __builtin_amdgcn_mfma_f32_16x16x32_bf16(b, aops[ks], acc, 0, 0, 0);   // D[col][edge]
      }
      if (rowOK){
        uint2 pk;
        pk.x = pk2bf(acc[0], acc[1]);
        pk.y = pk2bf(acc[2], acc[3]);
        *(uint2*)(orow + f_nt*16 + g*4) = pk;
      }
    }

    if (!more) break;
    cur = nxt;
    t = tn;
  }
}

// ---------------- crystal stats: VECTORIZED 16B reads, 4 rows in flight per wave ----------------
// Round-11: old version read gated 4B/lane/edge (64 scalar dwords per 256B row, 1 row in
// flight per wave) — the classic scalar-bf16 2-2.5x loss on a pure streaming reduction.
// New: lane = (sub = lane>>4, ch = lane&15); each lane reads uint4 (8 bf16 cols) of row
// e[p+sub] -> 4 rows in flight, 4x fewer load insts. Lane accumulates S/Q for cols
// ch*8..ch*8+7; butterfly over sub (xor 16,32), LDS-merge 4 waves.
// NEW pstat layout per block: t = ch*16 + j : j<8 -> S(col ch*8+j), j>=8 -> Q(col ch*8+j-8).
// k_red128f indexing updated to match.
__global__ __launch_bounds__(256) void k_cstats128(const unsigned short* __restrict__ gated,
                                                   const int* __restrict__ coffs, const int* __restrict__ celist,
                                                   float* __restrict__ pstat){
  int cr = blockIdx.x >> 3, s = blockIdx.x & 7;
  int t = threadIdx.x, w = t >> 6, lane = t & 63;
  int sub = lane >> 4, ch = lane & 15;
  int o0 = coffs[cr], o1 = coffs[cr+1];
  long long L = o1 - o0;
  int lo = o0 + (int)(L*s/8), hi = o0 + (int)(L*(s+1)/8);
  float S[8], Q[8];
#pragma unroll
  for (int j = 0; j < 8; ++j){ S[j] = 0.f; Q[j] = 0.f; }
  for (int p = lo + w*4; p < hi; p += 16){
    int q = p + sub;
    if (q < hi){
      int e = celist[q];
      uint4 vv = *(const uint4*)(gated + (size_t)e*128 + ch*8);
      unsigned uu0 = vv.x, uu1 = vv.y, uu2 = vv.z, uu3 = vv.w;
      float a0 = bf2f((unsigned short)(uu0 & 0xffffu)), b0 = bf2f((unsigned short)(uu0 >> 16));
      float a1 = bf2f((unsigned short)(uu1 & 0xffffu)), b1 = bf2f((unsigned short)(uu1 >> 16));
      float a2 = bf2f((unsigned short)(uu2 & 0xffffu)), b2 = bf2f((unsigned short)(uu2 >> 16));
      float a3 = bf2f((unsigned short)(uu3 & 0xffffu)), b3 = bf2f((unsigned short)(uu3 >> 16));
      S[0] += a0; Q[0] += a0*a0;  S[1] += b0; Q[1] += b0*b0;
      S[2] += a1; Q[2] += a1*a1;  S[3] += b1; Q[3] += b1*b1;
      S[4] += a2; Q[4] += a2*a2;  S[5] += b2; Q[5] += b2*b2;
      S[6] += a3; Q[6] += a3*a3;  S[7] += b3; Q[7] += b3*b3;
    }
  }
#pragma unroll
  for (int j = 0; j < 8; ++j){
    S[j] += __shfl_xor(S[j], 16, 64); S[j] += __shfl_xor(S[j], 32, 64);
    Q[j] += __shfl_xor(Q[j], 16, 64); Q[j] += __shfl_xor(Q[j], 32, 64);
  }
  __shared__ float sP[4][256];
  if (sub == 0){
#pragma unroll
    for (int j = 0; j < 8; ++j){
      sP[w][ch*16 + j]     = S[j];
      sP[w][ch*16 + 8 + j] = Q[j];
    }
  }
  __syncthreads();
  float v = sP[0][t] + sP[1][t] + sP[2][t] + sP[3][t];
  pstat[((size_t)blockIdx.x << 8) + t] = v;
}

// 64-col bf16 variant (fallback half-rows, unchanged layout)
__global__ __launch_bounds__(256) void k_cstats64(const unsigned short* __restrict__ gated,
                                                  const int* __restrict__ coffs, const int* __restrict__ celist,
                                                  float* __restrict__ pstat){
  int cr = blockIdx.x >> 3, s = blockIdx.x & 7;
  int t = threadIdx.x, w = t >> 6, lane = t & 63;
  int o0 = coffs[cr], o1 = coffs[cr+1];
  long long L = o1 - o0;
  int lo = o0 + (int)(L*s/8), hi = o0 + (int)(L*(s+1)/8);
  float S=0.f, Q=0.f;
  for (int p = lo + w*8; p < hi; p += 32){
#pragma unroll
    for (int u = 0; u < 8; ++u){
      if (p + u < hi){
        int e = celist[p+u];
        float a = bf2f(gated[(size_t)e*64 + lane]);
        S += a; Q += a*a;
      }
    }
  }
  __shared__ float sP[4][128];
  sP[w][lane*2+0]=S; sP[w][lane*2+1]=Q;
  __syncthreads();
  if (t < 128){
    float v = sP[0][t] + sP[1][t] + sP[2][t] + sP[3][t];
    pstat[((size_t)blockIdx.x << 7) + t] = v;
  }
}

// node stats: f32 rows / in-degree
__global__ __launch_bounds__(256) void k_cnstats(const float* __restrict__ nacc, const int* __restrict__ ncnt,
                                                 const int* __restrict__ coffs, const int* __restrict__ cnlist,
                                                 float* __restrict__ pstat){
  int cr = blockIdx.x >> 1, s = blockIdx.x & 1;
  int t = threadIdx.x, w = t >> 6, lane = t & 63;
  int o0 = coffs[cr], o1 = coffs[cr+1];
  long long L = o1 - o0;
  int lo = o0 + (int)(L*s/2), hi = o0 + (int)(L*(s+1)/2);
  float S=0.f, Q=0.f;
  for (int p = lo + w*4; p < hi; p += 16){
#pragma unroll
    for (int u = 0; u < 4; ++u){
      if (p + u < hi){
        int n = cnlist[p+u];
        float inv = 1.f / fmaxf((float)ncnt[n], 1.f);
        float a = nacc[(size_t)n*64 + lane]*inv;
        S += a; Q += a*a;
      }
    }
  }
  __shared__ float sP[4][128];
  sP[w][lane*2+0]=S; sP[w][lane*2+1]=Q;
  __syncthreads();
  if (t < 128){
    float v = sP[0][t] + sP[1][t] + sP[2][t] + sP[3][t];
    pstat[((size_t)blockIdx.x << 7) + t] = v;
  }
}

// ---------------- partial reduce -> scale/shift + fused filter precompute ----------------
// pstat layout (new, from vectorized k_cstats128): per block, t = ch*16 + j,
// j<8 -> S(col ch*8+j), j>=8 -> Q. vS = (col>>3)*16 + (col&7), Q at vS+8.
__global__ __launch_bounds__(256) void k_red128f(const float* __restrict__ pstat, const int* __restrict__ ccnt,
                                                 const float* __restrict__ gamma, const float* __restrict__ beta,
                                                 const float* __restrict__ Wm,
                                                 float* __restrict__ sc, float* __restrict__ sh,
                                                 float* __restrict__ w2, float* __restrict__ fb){
  int idx = blockIdx.x*256 + threadIdx.x;   // 256 cr x 128 col
  int cr = idx >> 7, col = idx & 127;
  int vS = ((col >> 3) << 4) + (col & 7);
  float S=0.f, Q=0.f;
  for (int s2 = 0; s2 < 8; ++s2){
    const float* b = pstat + ((size_t)(cr*8 + s2) << 8);
    S += b[vS]; Q += b[vS + 8];
  }
  float cnt = fmaxf((float)ccnt[cr], 1.f);
  float mean = S/cnt;
  float var = fmaxf(Q/cnt - mean*mean, 0.f);
  float r = 1.f / sqrtf(var + 1e-5f);
  float g = r*gamma[col];
  float shv = beta[col] - mean*g;
  sc[cr*128 + col] = g;
  sh[cr*128 + col] = shv;

  __shared__ float red[256];
  float contrib = 0.f;
  if (col < 64){
    float wmv = Wm[col];
    w2[cr*64 + col] = g*wmv;
    contrib = shv*wmv;
  }
  red[threadIdx.x] = contrib;
  __syncthreads();
  int lc = threadIdx.x & 127;
  for (int d = 32; d > 0; d >>= 1){
    if (lc < d) red[threadIdx.x] += red[threadIdx.x + d];
    __syncthreads();
  }
  if (lc == 0) fb[cr] = red[threadIdx.x];
}

__global__ __launch_bounds__(256) void k_red64(const float* __restrict__ pstat, int nsplit,
                                               const int* __restrict__ ccnt,
                                               const float* __restrict__ gamma, const float* __restrict__ beta,
                                               float* __restrict__ sc, float* __restrict__ sh,
                                               int stride, int colOff){
  int idx = blockIdx.x*256 + threadIdx.x;   // 256 cr x 64 col
  int cr = idx >> 6, col = idx & 63;
  int vS = col*2;
  float S=0.f, Q=0.f;
  for (int s2 = 0; s2 < nsplit; ++s2){
    const float* b = pstat + ((size_t)(cr*nsplit + s2) << 7);
    S += b[vS]; Q += b[vS+1];
  }
  float cnt = fmaxf((float)ccnt[cr], 1.f);
  float mean = S/cnt;
  float var = fmaxf(Q/cnt - mean*mean, 0.f);
  float r = 1.f / sqrtf(var + 1e-5f);
  float g = r*gamma[col];
  sc[cr*stride + colOff + col] = g;
  sh[cr*stride + colOff + col] = beta[col] - mean*g;
}

// ---------------- filter precompute (fallback path only) ----------------
__global__ __launch_bounds__(256) void k_fprep(const float* __restrict__ scE, const float* __restrict__ shE,
                                               const float* __restrict__ Wm, float* __restrict__ w2,
                                               float* __restrict__ fb){
  int t = threadIdx.x, w = t >> 6, lane = t & 63;
  int cr = blockIdx.x*4 + w;
  float wm = Wm[lane];
  w2[cr*64 + lane] = scE[cr*128 + lane]*wm;
  float b = shE[cr*128 + lane]*wm;
#pragma unroll
  for (int d = 1; d < 64; d <<= 1) b += __shfl_xor(b, d, 64);
  if (lane == 0) fb[cr] = b;
}

// ---------------- fallback standalone filter ----------------
__global__ __launch_bounds__(256) void k_filter(const unsigned short* __restrict__ gated, int gst,
                                                const int4* __restrict__ edat, const float* __restrict__ w2,
                                                const float* __restrict__ fb, float* __restrict__ filt, int E){
  size_t r = (size_t)blockIdx.x*256 + threadIdx.x;
  if (r >= (size_t)E) return;
  int cr = edat[r].w;
  const uint4* row = (const uint4*)(gated + r*(size_t)gst);
  const float4* wr = (const float4*)(w2 + cr*64);
  float logit = fb[cr];
#pragma unroll
  for (int j = 0; j < 8; ++j){
    uint4 v = row[j];
    float4 wa = wr[2*j], wb = wr[2*j+1];
    logit += bf2f((unsigned short)(v.x & 0xffffu))*wa.x + bf2f((unsigned short)(v.x >> 16))*wa.y;
    logit += bf2f((unsigned short)(v.y & 0xffffu))*wa.z + bf2f((unsigned short)(v.y >> 16))*wa.w;
    logit += bf2f((unsigned short)(v.z & 0xffffu))*wb.x + bf2f((unsigned short)(v.z >> 16))*wb.y;
    logit += bf2f((unsigned short)(v.w & 0xffffu))*wb.z + bf2f((unsigned short)(v.w >> 16))*wb.w;
  }
  filt[r] = 1.f / (1.f + __expf(-logit));
}

// ---------------- FUSED filter + message gather: 8 lanes/edge, 8 edges/iter ----------------
__global__ __launch_bounds__(256) void k_msgf8(const unsigned short* __restrict__ gated,
                                               const int4* __restrict__ edat,
                                               const int* __restrict__ offs,
                                               const float* __restrict__ scE, const float* __restrict__ shE,
                                               const float* __restrict__ w2, const float* __restrict__ fb,
                                               float* __restrict__ nacc, int NN){
  int w = threadIdx.x >> 6, lane = threadIdx.x & 63;
  int n = blockIdx.x*4 + w;
  if (n >= NN) return;
  int sub = lane >> 3, c8 = lane & 7;
  float a0=0.f,a1=0.f,a2=0.f,a3=0.f,a4=0.f,a5=0.f,a6=0.f,a7=0.f;
  int p0 = offs[n], p1 = offs[n+1];
  for (int p = p0; p < p1; p += 8){
    int q = p + sub;
    bool ok = q < p1;
    if (!ok) q = p;
    int cr = edat[q].w;
    // filter part: cols 8*c8 .. 8*c8+7
    uint4 vf = *(const uint4*)(gated + (size_t)q*128 + c8*8);
    const float4* wvp = (const float4*)(w2 + cr*64 + c8*8);
    float4 wv0 = wvp[0], wv1 = wvp[1];
    float part = bf2f((unsigned short)(vf.x & 0xffffu))*wv0.x
               + bf2f((unsigned short)(vf.x >> 16))*wv0.y
               + bf2f((unsigned short)(vf.y & 0xffffu))*wv0.z
               + bf2f((unsigned short)(vf.y >> 16))*wv0.w
               + bf2f((unsigned short)(vf.z & 0xffffu))*wv1.x
               + bf2f((unsigned short)(vf.z >> 16))*wv1.y
               + bf2f((unsigned short)(vf.w & 0xffffu))*wv1.z
               + bf2f((unsigned short)(vf.w >> 16))*wv1.w;
#pragma unroll
    for (int d = 1; d < 8; d <<= 1) part += __shfl_xor(part, d, 64);  // within 8-lane group
    float f = 1.f / (1.f + __expf(-(part + fb[cr])));
    // core part: cols 64 + 8*c8 .. 64 + 8*c8+7
    uint4 vc = *(const uint4*)(gated + (size_t)q*128 + 64 + c8*8);
    const float4* scp = (const float4*)(scE + cr*128 + 64 + c8*8);
    const float4* shp = (const float4*)(shE + cr*128 + 64 + c8*8);
    float4 s0 = scp[0], s1 = scp[1];
    float4 h0 = shp[0], h1 = shp[1];
    if (ok){
      a0 += f*fmaxf(bf2f((unsigned short)(vc.x & 0xffffu))*s0.x + h0.x, 0.f);
      a1 += f*fmaxf(bf2f((unsigned short)(vc.x >> 16))*s0.y + h0.y, 0.f);
      a2 += f*fmaxf(bf2f((unsigned short)(vc.y & 0xffffu))*s0.z + h0.z, 0.f);
      a3 += f*fmaxf(bf2f((unsigned short)(vc.y >> 16))*s0.w + h0.w, 0.f);
      a4 += f*fmaxf(bf2f((unsigned short)(vc.z & 0xffffu))*s1.x + h1.x, 0.f);
      a5 += f*fmaxf(bf2f((unsigned short)(vc.z >> 16))*s1.y + h1.y, 0.f);
      a6 += f*fmaxf(bf2f((unsigned short)(vc.w & 0xffffu))*s1.z + h1.z, 0.f);
      a7 += f*fmaxf(bf2f((unsigned short)(vc.w >> 16))*s1.w + h1.w, 0.f);
    }
  }
#pragma unroll
  for (int d = 8; d < 64; d <<= 1){
    a0 += __shfl_xor(a0, d, 64); a1 += __shfl_xor(a1, d, 64);
    a2 += __shfl_xor(a2, d, 64); a3 += __shfl_xor(a3, d, 64);
    a4 += __shfl_xor(a4, d, 64); a5 += __shfl_xor(a5, d, 64);
    a6 += __shfl_xor(a6, d, 64); a7 += __shfl_xor(a7, d, 64);
  }
  if (lane < 8){
    float4 o0; o0.x = a0; o0.y = a1; o0.z = a2; o0.w = a3;
    float4 o1; o1.x = a4; o1.y = a5; o1.z = a6; o1.w = a7;
    float4* dst = (float4*)(nacc + (size_t)n*64 + (size_t)c8*8);
    dst[0] = o0; dst[1] = o1;
  }
}

// ---------------- fallback msg (separate halves + filt buffer) ----------------
__global__ __launch_bounds__(256) void k_msg3(const unsigned short* __restrict__ gated, int gst, int colBase,
                                              const int4* __restrict__ edat, const float* __restrict__ filt,
                                              const int* __restrict__ offs,
                                              const float* __restrict__ scE, const float* __restrict__ shE,
                                              int scOff, float* __restrict__ nacc, int NN){
  int w = threadIdx.x >> 6, lane = threadIdx.x & 63;
  int n = blockIdx.x*4 + w;
  if (n >= NN) return;
  int sub = lane >> 5, c2 = lane & 31;
  float a0 = 0.f, a1 = 0.f;
  int p0 = offs[n], p1 = offs[n+1];
  for (int p = p0; p < p1; p += 2){
    int idx = p + sub;
    bool ok = idx < p1;
    int q = ok ? idx : p;
    unsigned v = *(const unsigned*)(gated + (size_t)q*gst + colBase + c2*2);
    float f = filt[q];
    int cr = edat[q].w;
    float2 sc2 = *(const float2*)(scE + cr*128 + scOff + c2*2);
    float2 sh2 = *(const float2*)(shE + cr*128 + scOff + c2*2);
    if (ok){
      float g0 = bf2f((unsigned short)(v & 0xffffu));
      float g1 = bf2f((unsigned short)(v >> 16));
      a0 += f*fmaxf(g0*sc2.x + sh2.x, 0.f);
      a1 += f*fmaxf(g1*sc2.y + sh2.y, 0.f);
    }
  }
  a0 += __shfl_xor(a0, 32, 64);
  a1 += __shfl_xor(a1, 32, 64);
  if (lane < 32) *(float2*)(nacc + (size_t)n*64 + (size_t)c2*2) = make_float2(a0, a1);
}

// ---------------- node epilogue: norm + 2x residual MLP + final relu ----------------
__global__ __launch_bounds__(256) void k_final(const float* __restrict__ nacc, const int* __restrict__ ncnt,
                                               const int* __restrict__ cidx, const float* __restrict__ nsc,
                                               const float* __restrict__ nsh, const float* __restrict__ W1a,
                                               const float* __restrict__ W1b, const float* __restrict__ W2a,
                                               const float* __restrict__ W2b, const float* __restrict__ atom,
                                               float* __restrict__ out, int NN)
{
  __shared__ float sW[4][2048];
  __shared__ float hbuf[8192];
  int tid = threadIdx.x;
  for (int i = tid; i < 2048; i += 256){
    sW[0][i] = W1a[i]; sW[1][i] = W1b[i]; sW[2][i] = W2a[i]; sW[3][i] = W2b[i];
  }
  __syncthreads();
  int n = blockIdx.x*256 + tid;
  if (n >= NN) return;
  const float ISQ2 = 0.70710678118654752440f;
  int cr = cidx[n];
  float inv = 1.f / fmaxf((float)ncnt[n], 1.f);
  float x[64];
  const float4* src = (const float4*)(nacc + (size_t)n*64);
#pragma unroll
  for (int j = 0; j < 16; ++j){
    float4 v = src[j];
    x[4*j] = v.x*inv; x[4*j+1] = v.y*inv; x[4*j+2] = v.z*inv; x[4*j+3] = v.w*inv;
  }
#pragma unroll
  for (int c = 0; c < 64; ++c)
    x[c] = x[c]*nsc[cr*64 + c] + nsh[cr*64 + c];

  for (int blk = 0; blk < 2; ++blk){
    const float* sa = sW[blk*2];
    const float* sb = sW[blk*2 + 1];
    for (int j = 0; j < 32; ++j){
      float s = 0.f;
#pragma unroll
      for (int k = 0; k < 64; ++k) s += x[k]*sa[k*32 + j];
      hbuf[tid*32 + (j ^ (tid & 31))] = fmaxf(s, 0.f);
    }
    float x2[64];
#pragma unroll
    for (int c = 0; c < 64; ++c) x2[c] = 0.f;
    for (int j = 0; j < 32; ++j){
      float hj = hbuf[tid*32 + (j ^ (tid & 31))];
#pragma unroll
      for (int c = 0; c < 64; ++c) x2[c] += hj*sb[j*64 + c];
    }
#pragma unroll
    for (int c = 0; c < 64; ++c)
      x[c] = (x[c] + fmaxf(x2[c], 0.f))*ISQ2;
  }
  const float4* ap = (const float4*)(atom + (size_t)n*64);
  float4* op = (float4*)(out + (size_t)n*64);
#pragma unroll
  for (int j = 0; j < 16; ++j){
    float4 av = ap[j]; float4 o;
    o.x = ISQ2*fmaxf(av.x + x[4*j],   0.f);
    o.y = ISQ2*fmaxf(av.y + x[4*j+1], 0.f);
    o.z = ISQ2*fmaxf(av.z + x[4*j+2], 0.f);
    o.w = ISQ2*fmaxf(av.w + x[4*j+3], 0.f);
    op[j] = o;
  }
}

extern "C" void kernel_launch(void* const* d_in, const int* in_sizes, int n_in,
                              void* d_out, int out_size, void* d_ws, size_t ws_size,
                              hipStream_t stream)
{
  const float* atom  = (const float*)d_in[0];
  const float* edgef = (const float*)d_in[1];
  const float* rbff  = (const float*)d_in[2];
  const int*   nbr   = (const int*)d_in[3];
  const int*   cidxn = (const int*)d_in[4];
  const int*   cidxe = (const int*)d_in[5];
  const float* Wrbf  = (const float*)d_in[6];
  const float* Wful  = (const float*)d_in[7];
  const float* Wmask = (const float*)d_in[8];
  const float* g1    = (const float*)d_in[9];
  const float* b1    = (const float*)d_in[10];
  const float* g2    = (const float*)d_in[11];
  const float* b2    = (const float*)d_in[12];
  const float* W1a   = (const float*)d_in[13];
  const float* W1b   = (const float*)d_in[14];
  const float* W2a   = (const float*)d_in[15];
  const float* W2b   = (const float*)d_in[16];
  float* out = (float*)d_out;

  const int E  = in_sizes[1] / 64;
  const int NN = in_sizes[0] / 64;
  const int nT = (E + 15) / 16;

  char* p = (char*)d_ws;
  auto take = [&](size_t bytes){ void* r = (void*)p; p += (bytes + 255) & ~(size_t)255; return r; };

  const bool full = ws_size >= (size_t)360000000;
  const int gstride = full ? 128 : 64;

  unsigned short* gated = (unsigned short*)take((size_t)E*gstride*2);
  float* pstat  = (float*)take((size_t)2048*256*4);
  float* pstatN = (float*)take((size_t)512*128*4);
  float* nacc   = (float*)take((size_t)NN*64*4);
  int*   ncnt   = (int*)take((size_t)NN*4);
  int*   offs   = (int*)take((size_t)(NN+1)*4);
  int*   cursor = (int*)take((size_t)NN*4);
  int4*  edat   = (int4*)take((size_t)E*16);
  int*   celist = (int*)take((size_t)E*4);
  int*   cnlist = (int*)take((size_t)NN*4);
  int*   ceoffs = (int*)take(257*4);
  int*   cecur  = (int*)take(256*4);
  int*   cnoffs = (int*)take(257*4);
  int*   cncur  = (int*)take(256*4);
  int*   ccnte  = (int*)take(1024);
  int*   ccntn  = (int*)take(1024);
  float* scE    = (float*)take(256*128*4);
  float* shE    = (float*)take(256*128*4);
  float* nsc    = (float*)take(256*64*4);
  float* nsh    = (float*)take(256*64*4);
  float* w2     = (float*)take(256*64*4);
  float* fb     = (float*)take(256*4);
  float* filt   = (float*)take((size_t)E*4);
  unsigned short* Bpack = (unsigned short*)take(6*8*64*8*2);

  (void)hipMemsetAsync(ncnt,  0, (size_t)NN*4, stream);
  (void)hipMemsetAsync(ccnte, 0, 1024, stream);
  (void)hipMemsetAsync(ccntn, 0, 1024, stream);

  k_prep<<<48, 64, 0, stream>>>(Wful, Bpack);
  k_pre<<<2048, 256, 0, stream>>>(cidxe, E, cidxn, NN, nbr, ccnte, ccntn, ncnt);
  k_scans<<<3, 1024, 0, stream>>>(ncnt, NN, offs, cursor, ccnte, ccntn, ceoffs, cecur, cnoffs, cncur);
  k_scatter2<<<(E + 1023)/1024, 256, 0, stream>>>(nbr, cidxe, E, cursor, edat, cecur, celist);
  k_cscatter<<<(NN + 4095)/4096, 256, 0, stream>>>(cidxn, NN, cncur, cnlist);

  if (full){
    k_gemm<0,8><<<1024, 512, 0, stream>>>(atom, edgef, rbff, edat, Wrbf, Bpack, gated, 128, 0, nT, E);
    k_cstats128<<<2048, 256, 0, stream>>>(gated, ceoffs, celist, pstat);
    k_red128f<<<128, 256, 0, stream>>>(pstat, ccnte, g1, b1, Wmask, scE, shE, w2, fb);
    k_msgf8<<<(NN + 3)/4, 256, 0, stream>>>(gated, edat, offs, scE, shE, w2, fb, nacc, NN);
  } else {
    k_gemm<0,4><<<1024, 512, 0, stream>>>(atom, edgef, rbff, edat, Wrbf, Bpack, gated, 64, 0, nT, E);
    k_cstats64<<<2048, 256, 0, stream>>>(gated, ceoffs, celist, pstat);
    k_red64<<<64, 256, 0, stream>>>(pstat, 8, ccnte, g1, b1, scE, shE, 128, 0);
    k_fprep<<<64, 256, 0, stream>>>(scE, shE, Wmask, w2, fb);
    k_filter<<<(E + 255)/256, 256, 0, stream>>>(gated, 64, edat, w2, fb, filt, E);
    k_gemm<4,8><<<1024, 512, 0, stream>>>(atom, edgef, rbff, edat, Wrbf, Bpack, gated, 64, 64, nT, E);
    k_cstats64<<<2048, 256, 0, stream>>>(gated, ceoffs, celist, pstat);
    k_red64<<<64, 256, 0, stream>>>(pstat, 8, ccnte, g1 + 64, b1 + 64, scE, shE, 128, 64);
    k_msg3<<<(NN + 3)/4, 256, 0, stream>>>(gated, 64, 0, edat, filt, offs, scE, shE, 64, nacc, NN);
  }

  k_cnstats<<<512, 256, 0, stream>>>(nacc, ncnt, cnoffs, cnlist, pstatN);
  k_red64<<<64, 256, 0, stream>>>(pstatN, 2, ccntn, g2, b2, nsc, nsh, 64, 0);
  k_final<<<(NN + 255)/256, 256, 0, stream>>>(nacc, ncnt, cidxn, nsc, nsh, W1a, W1b, W2a, W2b, atom, out, NN);
}

// Round 12
// 831.044 us; speedup vs baseline: 1.2159x; 1.0087x over previous
//
#include <hip/hip_runtime.h>
#include <hip/hip_bf16.h>

typedef __attribute__((ext_vector_type(8))) short bfrag;
typedef __attribute__((ext_vector_type(4))) float f4;

__device__ __forceinline__ unsigned short f2bf(float f){
  unsigned b = __float_as_uint(f);
  b = (b + 0x7fffu + ((b >> 16) & 1u)) >> 16;
  return (unsigned short)b;
}
__device__ __forceinline__ unsigned pk2bf(float a, float b){
  return (unsigned)f2bf(a) | ((unsigned)f2bf(b) << 16);
}
__device__ __forceinline__ float bf2f(unsigned short u){
  return __uint_as_float(((unsigned)u) << 16);
}
__device__ __forceinline__ bfrag pack8(float4 x, float4 y){
  bfrag r;
  r[0]=(short)f2bf(x.x); r[1]=(short)f2bf(x.y); r[2]=(short)f2bf(x.z); r[3]=(short)f2bf(x.w);
  r[4]=(short)f2bf(y.x); r[5]=(short)f2bf(y.y); r[6]=(short)f2bf(y.z); r[7]=(short)f2bf(y.w);
  return r;
}

// ---------------- B pre-pack: W_full (192x128 f32) -> MFMA frag layout bf16 ----------------
__global__ __launch_bounds__(64) void k_prep(const float* __restrict__ Wf, unsigned short* __restrict__ Bpack){
  int l = threadIdx.x; int f = blockIdx.x; int ks = f >> 3; int nt = f & 7;
  int kg = l >> 4; int nn = l & 15;
#pragma unroll
  for (int j = 0; j < 8; ++j){
    int k;
    if (ks < 4) k = ks*32 + kg*8 + j;
    else        k = 128 + (ks-4)*32 + ((j>>2)<<4) + kg*4 + (j&3);
    Bpack[((size_t)f*64 + l)*8 + j] = f2bf(Wf[(size_t)k*128 + nt*16 + nn]);
  }
}

// ---------------- merged prepass: all three histograms in one launch ----------------
__global__ __launch_bounds__(256) void k_pre(const int* __restrict__ cidxe, int E,
                                             const int* __restrict__ cidxn, int NN,
                                             const int* __restrict__ nbr,
                                             int* __restrict__ ccnte, int* __restrict__ ccntn,
                                             int* __restrict__ ncnt){
  __shared__ int he[256], hn[256];
  int t = threadIdx.x;
  he[t] = 0; hn[t] = 0;
  __syncthreads();
  for (size_t i = (size_t)blockIdx.x*256 + t; i < (size_t)E; i += (size_t)gridDim.x*256){
    atomicAdd(&he[cidxe[i]], 1);
    atomicAdd(&ncnt[nbr[2*i]], 1);
  }
  for (size_t i = (size_t)blockIdx.x*256 + t; i < (size_t)NN; i += (size_t)gridDim.x*256)
    atomicAdd(&hn[cidxn[i]], 1);
  __syncthreads();
  if (he[t]) atomicAdd(&ccnte[t], he[t]);
  if (hn[t]) atomicAdd(&ccntn[t], hn[t]);
}

// ---------------- merged scans: block 0 = node-count scan (1024 thr); blocks 1,2 = 256-bin crystal scans ----------------
__global__ __launch_bounds__(1024) void k_scans(const int* __restrict__ ncnt, int NN,
                                                int* __restrict__ offs, int* __restrict__ cursor,
                                                const int* __restrict__ ccnte, const int* __restrict__ ccntn,
                                                int* __restrict__ ceoffs, int* __restrict__ cecur,
                                                int* __restrict__ cnoffs, int* __restrict__ cncur){
  int tid = threadIdx.x;
  if (blockIdx.x == 0){
    __shared__ int part[1024];
    int chunk = (NN + 1023) >> 10;
    int base = tid*chunk;
    int s = 0;
    for (int i = 0; i < chunk; ++i){ int p = base + i; if (p < NN) s += ncnt[p]; }
    part[tid] = s;
    __syncthreads();
    for (int d = 1; d < 1024; d <<= 1){
      int v = (tid >= d) ? part[tid - d] : 0;
      __syncthreads();
      part[tid] += v;
      __syncthreads();
    }
    int run = (tid == 0) ? 0 : part[tid-1];
    for (int i = 0; i < chunk; ++i){
      int p = base + i;
      if (p < NN){ offs[p] = run; cursor[p] = run; run += ncnt[p]; }
    }
    if (tid == 1023) offs[NN] = part[1023];
  } else {
    __shared__ int sh[256];
    const int* cnt = (blockIdx.x == 2) ? ccntn : ccnte;
    int* off = (blockIdx.x == 2) ? cnoffs : ceoffs;
    int* cur = (blockIdx.x == 2) ? cncur  : cecur;
    int v = 0;
    if (tid < 256){ v = cnt[tid]; sh[tid] = v; }
    __syncthreads();
    for (int d = 1; d < 256; d <<= 1){
      int x = (tid >= d && tid < 256) ? sh[tid - d] : 0;
      __syncthreads();
      if (tid < 256) sh[tid] += x;
      __syncthreads();
    }
    if (tid < 256){
      off[tid] = sh[tid] - v; cur[tid] = sh[tid] - v;
      if (tid == 255) off[256] = sh[255];
    }
  }
}

// ---------------- MERGED CSR scatter + crystal-list build ----------------
__global__ __launch_bounds__(256) void k_scatter2(const int* __restrict__ nbr, const int* __restrict__ cidxe,
                                                  int E, int* __restrict__ cursor, int4* __restrict__ edat,
                                                  int* __restrict__ gcur, int* __restrict__ celist){
  __shared__ int lhist[256], lbase[256], lcur[256];
  int t = threadIdx.x;
  lhist[t] = 0; lcur[t] = 0;
  __syncthreads();
  int base = blockIdx.x*1024;
  int end = min(base + 1024, E);
  for (int i = base + t; i < end; i += 256) atomicAdd(&lhist[cidxe[i]], 1);
  __syncthreads();
  if (lhist[t]) lbase[t] = atomicAdd(&gcur[t], lhist[t]);
  __syncthreads();
  for (int i = base + t; i < end; i += 256){
    int cr = cidxe[i];
    int n = nbr[2*(size_t)i];
    int j = nbr[2*(size_t)i + 1];
    int pos = atomicAdd(&cursor[n], 1);
    edat[pos] = make_int4(n, j, i, cr);
    int lp = atomicAdd(&lcur[cr], 1);
    celist[lbase[cr] + lp] = pos;
  }
}

// ---------------- hierarchical crystal scatter (node list) ----------------
__global__ __launch_bounds__(256) void k_cscatter(const int* __restrict__ idx, int n,
                                                  int* __restrict__ gcur, int* __restrict__ outl){
  __shared__ int lhist[256], lbase[256], lcur[256];
  int t = threadIdx.x;
  lhist[t] = 0; lcur[t] = 0;
  __syncthreads();
  int base = blockIdx.x*4096;
  int end = min(base + 4096, n);
  for (int i = base + t; i < end; i += 256) atomicAdd(&lhist[idx[i]], 1);
  __syncthreads();
  if (lhist[t]) lbase[t] = atomicAdd(&gcur[t], lhist[t]);
  __syncthreads();
  for (int i = base + t; i < end; i += 256){
    int b = idx[i];
    int p = atomicAdd(&lcur[b], 1);
    outl[lbase[b] + p] = i;
  }
}

// ---------------- operand set for one 16-edge tile (CSR order), packed at load ----------------
struct TileRegs {
  bfrag a0, a1, a2, a3;    // atom_i[0:32], atom_i[32:64], atom_j[0:32], atom_j[32:64] bf16
  bfrag rf;                // rbf (zero-padded) bf16
  float4 re0, re1, re2, re3;  // edge feats f32 (multiply MFMA output)
};

__device__ __forceinline__ TileRegs load_tile(const float* __restrict__ atom, const float* __restrict__ edgef,
                                              const float* __restrict__ rbff, const int4* __restrict__ edat,
                                              size_t r0, int e16, int g, int E){
  TileRegs R;
  size_t er = r0 + e16;
  if (er >= (size_t)E) er = 0;
  const int4 ed = edat[er];
  const float4* Ai = (const float4*)(atom + (size_t)ed.x*64);
  const float4* Aj = (const float4*)(atom + (size_t)ed.y*64);
  float4 ra0 = Ai[g*2],   ra1 = Ai[g*2+1];
  float4 rb0 = Ai[8+g*2], rb1 = Ai[8+g*2+1];
  float4 rc0 = Aj[g*2],   rc1 = Aj[g*2+1];
  float4 rd0 = Aj[8+g*2], rd1 = Aj[8+g*2+1];
  float4 rr0 = make_float4(0.f,0.f,0.f,0.f);
  float4 rr1 = make_float4(0.f,0.f,0.f,0.f);
  if (g < 2){
    const float4* rp = (const float4*)(rbff + (size_t)ed.z*16 + g*8);
    rr0 = rp[0]; rr1 = rp[1];
  }
  const float4* ep = (const float4*)(edgef + (size_t)ed.z*64);
  R.re0 = ep[g]; R.re1 = ep[4+g]; R.re2 = ep[8+g]; R.re3 = ep[12+g];
  R.a0 = pack8(ra0, ra1);
  R.a1 = pack8(rb0, rb1);
  R.a2 = pack8(rc0, rc1);
  R.a3 = pack8(rd0, rd1);
  R.rf = pack8(rr0, rr1);
  return R;
}

// ---------------- edge GEMM: 512-thread block, LDS-B + sched_barrier pin (round-10 best) ----------------
template<int FNT0, int FNT1>
__global__ __launch_bounds__(512) void k_gemm(const float* __restrict__ atom, const float* __restrict__ edgef,
                                              const float* __restrict__ rbff, const int4* __restrict__ edat,
                                              const float* __restrict__ Wrbf,
                                              const unsigned short* __restrict__ Bpack,
                                              unsigned short* __restrict__ gated, int gstride, int colOff,
                                              int nT, int E)
{
  __shared__ uint4 sBv[3072];   // 48KB, 16B-aligned: [ks][f_nt][lane][8] bf16
  const unsigned short* sB = (const unsigned short*)sBv;
  const int lane = threadIdx.x & 63;
  const int wid  = (blockIdx.x*512 + threadIdx.x) >> 6;
  const int nW   = gridDim.x*8;
  const int e16  = lane & 15;
  const int g    = lane >> 4;
  const f4 zero = {0.f, 0.f, 0.f, 0.f};

  {
    const uint4* src = (const uint4*)Bpack;
    for (int i = threadIdx.x; i < 3072; i += 512) sBv[i] = src[i];
  }

  bfrag wf[4];
#pragma unroll
  for (int ct = 0; ct < 4; ++ct){
#pragma unroll
    for (int i = 0; i < 8; ++i){
      float v = (g < 2) ? Wrbf[(g*8 + i)*64 + ct*16 + e16] : 0.f;
      wf[ct][i] = (short)f2bf(v);
    }
  }
  __syncthreads();

  size_t t = (size_t)wid;
  if (t >= (size_t)nT) return;
  TileRegs cur = load_tile(atom, edgef, rbff, edat, t*16, e16, g, E);

  while (true){
    const size_t tn = t + (size_t)nW;
    const bool more = tn < (size_t)nT;
    TileRegs nxt;
    if (more) nxt = load_tile(atom, edgef, rbff, edat, tn*16, e16, g, E);
    // Pin: the t+1 prefetch loads + packs must issue before the compute below.
    __builtin_amdgcn_sched_barrier(0);

    const size_t r0 = t*16;
    size_t er = r0 + e16;
    const bool rowOK = er < (size_t)E;
    if (!rowOK) er = 0;

    f4 h0 = __builtin_amdgcn_mfma_f32_16x16x32_bf16(wf[0], cur.rf, zero, 0, 0, 0);
    f4 h1 = __builtin_amdgcn_mfma_f32_16x16x32_bf16(wf[1], cur.rf, zero, 0, 0, 0);
    f4 h2 = __builtin_amdgcn_mfma_f32_16x16x32_bf16(wf[2], cur.rf, zero, 0, 0, 0);
    f4 h3 = __builtin_amdgcn_mfma_f32_16x16x32_bf16(wf[3], cur.rf, zero, 0, 0, 0);

    bfrag aops[6];
    aops[0] = cur.a0; aops[1] = cur.a1; aops[2] = cur.a2; aops[3] = cur.a3;
    const float* pe0 = (const float*)&cur.re0;
    const float* pe1 = (const float*)&cur.re1;
    const float* pe2 = (const float*)&cur.re2;
    const float* pe3 = (const float*)&cur.re3;
#pragma unroll
    for (int r = 0; r < 4; ++r){
      aops[4][r]   = (short)f2bf(h0[r]*pe0[r]);
      aops[4][4+r] = (short)f2bf(h1[r]*pe1[r]);
      aops[5][r]   = (short)f2bf(h2[r]*pe2[r]);
      aops[5][4+r] = (short)f2bf(h3[r]*pe3[r]);
    }

    unsigned short* orow = gated + er*(size_t)gstride - colOff;
#pragma unroll
    for (int f_nt = FNT0; f_nt < FNT1; ++f_nt){
      const unsigned short* bls = sB + ((size_t)(f_nt*64 + lane))*8;
      f4 acc = zero;
#pragma unroll
      for (int ks = 0; ks < 6; ++ks){
        bfrag b = *(const bfrag*)(bls + (size_t)ks*4096);
        acc = __builtin_amdgcn_mfma_f32_16x16x32_bf16(b, aops[ks], acc, 0, 0, 0);   // D[col][edge]
      }
      if (rowOK){
        uint2 pk;
        pk.x = pk2bf(acc[0], acc[1]);
        pk.y = pk2bf(acc[2], acc[3]);
        *(uint2*)(orow + f_nt*16 + g*4) = pk;
      }
    }

    if (!more) break;
    cur = nxt;
    t = tn;
  }
}

// ---------------- crystal stats: VECTORIZED 16B reads, 4 rows in flight per wave ----------------
__global__ __launch_bounds__(256) void k_cstats128(const unsigned short* __restrict__ gated,
                                                   const int* __restrict__ coffs, const int* __restrict__ celist,
                                                   float* __restrict__ pstat){
  int cr = blockIdx.x >> 3, s = blockIdx.x & 7;
  int t = threadIdx.x, w = t >> 6, lane = t & 63;
  int sub = lane >> 4, ch = lane & 15;
  int o0 = coffs[cr], o1 = coffs[cr+1];
  long long L = o1 - o0;
  int lo = o0 + (int)(L*s/8), hi = o0 + (int)(L*(s+1)/8);
  float S[8], Q[8];
#pragma unroll
  for (int j = 0; j < 8; ++j){ S[j] = 0.f; Q[j] = 0.f; }
  for (int p = lo + w*4; p < hi; p += 16){
    int q = p + sub;
    if (q < hi){
      int e = celist[q];
      uint4 vv = *(const uint4*)(gated + (size_t)e*128 + ch*8);
      unsigned uu0 = vv.x, uu1 = vv.y, uu2 = vv.z, uu3 = vv.w;
      float a0 = bf2f((unsigned short)(uu0 & 0xffffu)), b0 = bf2f((unsigned short)(uu0 >> 16));
      float a1 = bf2f((unsigned short)(uu1 & 0xffffu)), b1 = bf2f((unsigned short)(uu1 >> 16));
      float a2 = bf2f((unsigned short)(uu2 & 0xffffu)), b2 = bf2f((unsigned short)(uu2 >> 16));
      float a3 = bf2f((unsigned short)(uu3 & 0xffffu)), b3 = bf2f((unsigned short)(uu3 >> 16));
      S[0] += a0; Q[0] += a0*a0;  S[1] += b0; Q[1] += b0*b0;
      S[2] += a1; Q[2] += a1*a1;  S[3] += b1; Q[3] += b1*b1;
      S[4] += a2; Q[4] += a2*a2;  S[5] += b2; Q[5] += b2*b2;
      S[6] += a3; Q[6] += a3*a3;  S[7] += b3; Q[7] += b3*b3;
    }
  }
#pragma unroll
  for (int j = 0; j < 8; ++j){
    S[j] += __shfl_xor(S[j], 16, 64); S[j] += __shfl_xor(S[j], 32, 64);
    Q[j] += __shfl_xor(Q[j], 16, 64); Q[j] += __shfl_xor(Q[j], 32, 64);
  }
  __shared__ float sP[4][256];
  if (sub == 0){
#pragma unroll
    for (int j = 0; j < 8; ++j){
      sP[w][ch*16 + j]     = S[j];
      sP[w][ch*16 + 8 + j] = Q[j];
    }
  }
  __syncthreads();
  float v = sP[0][t] + sP[1][t] + sP[2][t] + sP[3][t];
  pstat[((size_t)blockIdx.x << 8) + t] = v;
}

// 64-col bf16 variant (fallback half-rows, unchanged layout)
__global__ __launch_bounds__(256) void k_cstats64(const unsigned short* __restrict__ gated,
                                                  const int* __restrict__ coffs, const int* __restrict__ celist,
                                                  float* __restrict__ pstat){
  int cr = blockIdx.x >> 3, s = blockIdx.x & 7;
  int t = threadIdx.x, w = t >> 6, lane = t & 63;
  int o0 = coffs[cr], o1 = coffs[cr+1];
  long long L = o1 - o0;
  int lo = o0 + (int)(L*s/8), hi = o0 + (int)(L*(s+1)/8);
  float S=0.f, Q=0.f;
  for (int p = lo + w*8; p < hi; p += 32){
#pragma unroll
    for (int u = 0; u < 8; ++u){
      if (p + u < hi){
        int e = celist[p+u];
        float a = bf2f(gated[(size_t)e*64 + lane]);
        S += a; Q += a*a;
      }
    }
  }
  __shared__ float sP[4][128];
  sP[w][lane*2+0]=S; sP[w][lane*2+1]=Q;
  __syncthreads();
  if (t < 128){
    float v = sP[0][t] + sP[1][t] + sP[2][t] + sP[3][t];
    pstat[((size_t)blockIdx.x << 7) + t] = v;
  }
}

// node stats: f32 rows / in-degree
__global__ __launch_bounds__(256) void k_cnstats(const float* __restrict__ nacc, const int* __restrict__ ncnt,
                                                 const int* __restrict__ coffs, const int* __restrict__ cnlist,
                                                 float* __restrict__ pstat){
  int cr = blockIdx.x >> 1, s = blockIdx.x & 1;
  int t = threadIdx.x, w = t >> 6, lane = t & 63;
  int o0 = coffs[cr], o1 = coffs[cr+1];
  long long L = o1 - o0;
  int lo = o0 + (int)(L*s/2), hi = o0 + (int)(L*(s+1)/2);
  float S=0.f, Q=0.f;
  for (int p = lo + w*4; p < hi; p += 16){
#pragma unroll
    for (int u = 0; u < 4; ++u){
      if (p + u < hi){
        int n = cnlist[p+u];
        float inv = 1.f / fmaxf((float)ncnt[n], 1.f);
        float a = nacc[(size_t)n*64 + lane]*inv;
        S += a; Q += a*a;
      }
    }
  }
  __shared__ float sP[4][128];
  sP[w][lane*2+0]=S; sP[w][lane*2+1]=Q;
  __syncthreads();
  if (t < 128){
    float v = sP[0][t] + sP[1][t] + sP[2][t] + sP[3][t];
    pstat[((size_t)blockIdx.x << 7) + t] = v;
  }
}

// ---------------- partial reduce -> scale/shift + fused filter precompute ----------------
// pstat layout: per block, t = ch*16 + j, j<8 -> S(col ch*8+j), j>=8 -> Q.
__global__ __launch_bounds__(256) void k_red128f(const float* __restrict__ pstat, const int* __restrict__ ccnt,
                                                 const float* __restrict__ gamma, const float* __restrict__ beta,
                                                 const float* __restrict__ Wm,
                                                 float* __restrict__ sc, float* __restrict__ sh,
                                                 float* __restrict__ w2, float* __restrict__ fb){
  int idx = blockIdx.x*256 + threadIdx.x;   // 256 cr x 128 col
  int cr = idx >> 7, col = idx & 127;
  int vS = ((col >> 3) << 4) + (col & 7);
  float S=0.f, Q=0.f;
  for (int s2 = 0; s2 < 8; ++s2){
    const float* b = pstat + ((size_t)(cr*8 + s2) << 8);
    S += b[vS]; Q += b[vS + 8];
  }
  float cnt = fmaxf((float)ccnt[cr], 1.f);
  float mean = S/cnt;
  float var = fmaxf(Q/cnt - mean*mean, 0.f);
  float r = 1.f / sqrtf(var + 1e-5f);
  float g = r*gamma[col];
  float shv = beta[col] - mean*g;
  sc[cr*128 + col] = g;
  sh[cr*128 + col] = shv;

  __shared__ float red[256];
  float contrib = 0.f;
  if (col < 64){
    float wmv = Wm[col];
    w2[cr*64 + col] = g*wmv;
    contrib = shv*wmv;
  }
  red[threadIdx.x] = contrib;
  __syncthreads();
  int lc = threadIdx.x & 127;
  for (int d = 32; d > 0; d >>= 1){
    if (lc < d) red[threadIdx.x] += red[threadIdx.x + d];
    __syncthreads();
  }
  if (lc == 0) fb[cr] = red[threadIdx.x];
}

__global__ __launch_bounds__(256) void k_red64(const float* __restrict__ pstat, int nsplit,
                                               const int* __restrict__ ccnt,
                                               const float* __restrict__ gamma, const float* __restrict__ beta,
                                               float* __restrict__ sc, float* __restrict__ sh,
                                               int stride, int colOff){
  int idx = blockIdx.x*256 + threadIdx.x;   // 256 cr x 64 col
  int cr = idx >> 6, col = idx & 63;
  int vS = col*2;
  float S=0.f, Q=0.f;
  for (int s2 = 0; s2 < nsplit; ++s2){
    const float* b = pstat + ((size_t)(cr*nsplit + s2) << 7);
    S += b[vS]; Q += b[vS+1];
  }
  float cnt = fmaxf((float)ccnt[cr], 1.f);
  float mean = S/cnt;
  float var = fmaxf(Q/cnt - mean*mean, 0.f);
  float r = 1.f / sqrtf(var + 1e-5f);
  float g = r*gamma[col];
  sc[cr*stride + colOff + col] = g;
  sh[cr*stride + colOff + col] = beta[col] - mean*g;
}

// ---------------- filter precompute (fallback path only) ----------------
__global__ __launch_bounds__(256) void k_fprep(const float* __restrict__ scE, const float* __restrict__ shE,
                                               const float* __restrict__ Wm, float* __restrict__ w2,
                                               float* __restrict__ fb){
  int t = threadIdx.x, w = t >> 6, lane = t & 63;
  int cr = blockIdx.x*4 + w;
  float wm = Wm[lane];
  w2[cr*64 + lane] = scE[cr*128 + lane]*wm;
  float b = shE[cr*128 + lane]*wm;
#pragma unroll
  for (int d = 1; d < 64; d <<= 1) b += __shfl_xor(b, d, 64);
  if (lane == 0) fb[cr] = b;
}

// ---------------- fallback standalone filter ----------------
__global__ __launch_bounds__(256) void k_filter(const unsigned short* __restrict__ gated, int gst,
                                                const int4* __restrict__ edat, const float* __restrict__ w2,
                                                const float* __restrict__ fb, float* __restrict__ filt, int E){
  size_t r = (size_t)blockIdx.x*256 + threadIdx.x;
  if (r >= (size_t)E) return;
  int cr = edat[r].w;
  const uint4* row = (const uint4*)(gated + r*(size_t)gst);
  const float4* wr = (const float4*)(w2 + cr*64);
  float logit = fb[cr];
#pragma unroll
  for (int j = 0; j < 8; ++j){
    uint4 v = row[j];
    float4 wa = wr[2*j], wb = wr[2*j+1];
    logit += bf2f((unsigned short)(v.x & 0xffffu))*wa.x + bf2f((unsigned short)(v.x >> 16))*wa.y;
    logit += bf2f((unsigned short)(v.y & 0xffffu))*wa.z + bf2f((unsigned short)(v.y >> 16))*wa.w;
    logit += bf2f((unsigned short)(v.z & 0xffffu))*wb.x + bf2f((unsigned short)(v.z >> 16))*wb.y;
    logit += bf2f((unsigned short)(v.w & 0xffffu))*wb.z + bf2f((unsigned short)(v.w >> 16))*wb.w;
  }
  filt[r] = 1.f / (1.f + __expf(-logit));
}

// ---------------- FUSED filter + message gather: 8 lanes/edge, 8 edges/iter, DEPTH-1 PREFETCH ----------------
// Round-12: per-iteration dependent chain (load vf -> dot -> 3 shfl -> exp -> core acc)
// serialized each 8-edge group behind the previous one. Same fix that took k_gemm
// 297->261 in round 8: prefetch next iteration's edat + both gated halves, then
// sched_barrier(0) pin, then compute current. Semantics identical (same clamp/guards).
__global__ __launch_bounds__(256) void k_msgf8(const unsigned short* __restrict__ gated,
                                               const int4* __restrict__ edat,
                                               const int* __restrict__ offs,
                                               const float* __restrict__ scE, const float* __restrict__ shE,
                                               const float* __restrict__ w2, const float* __restrict__ fb,
                                               float* __restrict__ nacc, int NN){
  int w = threadIdx.x >> 6, lane = threadIdx.x & 63;
  int n = blockIdx.x*4 + w;
  if (n >= NN) return;
  int sub = lane >> 3, c8 = lane & 7;
  float a0=0.f,a1=0.f,a2=0.f,a3=0.f,a4=0.f,a5=0.f,a6=0.f,a7=0.f;
  int p0 = offs[n], p1 = offs[n+1];

  int p = p0;
  bool any = p < p1;
  int4 ed; uint4 vf, vc;
  if (any){
    int q = p + sub; if (q >= p1) q = p;
    ed = edat[q];
    vf = *(const uint4*)(gated + (size_t)q*128 + c8*8);
    vc = *(const uint4*)(gated + (size_t)q*128 + 64 + c8*8);
  }
  while (any){
    const int pn = p + 8;
    const bool anyN = pn < p1;
    int4 edN; uint4 vfN, vcN;
    if (anyN){
      int qn = pn + sub; if (qn >= p1) qn = pn;
      edN = edat[qn];
      vfN = *(const uint4*)(gated + (size_t)qn*128 + c8*8);
      vcN = *(const uint4*)(gated + (size_t)qn*128 + 64 + c8*8);
    }
    // Pin: next-iteration loads issue before this iteration's compute chain.
    __builtin_amdgcn_sched_barrier(0);

    const bool ok = (p + sub) < p1;
    int cr = ed.w;
    // filter part: cols 8*c8 .. 8*c8+7
    const float4* wvp = (const float4*)(w2 + cr*64 + c8*8);
    float4 wv0 = wvp[0], wv1 = wvp[1];
    float part = bf2f((unsigned short)(vf.x & 0xffffu))*wv0.x
               + bf2f((unsigned short)(vf.x >> 16))*wv0.y
               + bf2f((unsigned short)(vf.y & 0xffffu))*wv0.z
               + bf2f((unsigned short)(vf.y >> 16))*wv0.w
               + bf2f((unsigned short)(vf.z & 0xffffu))*wv1.x
               + bf2f((unsigned short)(vf.z >> 16))*wv1.y
               + bf2f((unsigned short)(vf.w & 0xffffu))*wv1.z
               + bf2f((unsigned short)(vf.w >> 16))*wv1.w;
#pragma unroll
    for (int d = 1; d < 8; d <<= 1) part += __shfl_xor(part, d, 64);  // within 8-lane group
    float f = 1.f / (1.f + __expf(-(part + fb[cr])));
    // core part: cols 64 + 8*c8 .. 64 + 8*c8+7
    const float4* scp = (const float4*)(scE + cr*128 + 64 + c8*8);
    const float4* shp = (const float4*)(shE + cr*128 + 64 + c8*8);
    float4 s0 = scp[0], s1 = scp[1];
    float4 h0 = shp[0], h1 = shp[1];
    if (ok){
      a0 += f*fmaxf(bf2f((unsigned short)(vc.x & 0xffffu))*s0.x + h0.x, 0.f);
      a1 += f*fmaxf(bf2f((unsigned short)(vc.x >> 16))*s0.y + h0.y, 0.f);
      a2 += f*fmaxf(bf2f((unsigned short)(vc.y & 0xffffu))*s0.z + h0.z, 0.f);
      a3 += f*fmaxf(bf2f((unsigned short)(vc.y >> 16))*s0.w + h0.w, 0.f);
      a4 += f*fmaxf(bf2f((unsigned short)(vc.z & 0xffffu))*s1.x + h1.x, 0.f);
      a5 += f*fmaxf(bf2f((unsigned short)(vc.z >> 16))*s1.y + h1.y, 0.f);
      a6 += f*fmaxf(bf2f((unsigned short)(vc.w & 0xffffu))*s1.z + h1.z, 0.f);
      a7 += f*fmaxf(bf2f((unsigned short)(vc.w >> 16))*s1.w + h1.w, 0.f);
    }
    if (!anyN) break;
    ed = edN; vf = vfN; vc = vcN; p = pn;
  }
#pragma unroll
  for (int d = 8; d < 64; d <<= 1){
    a0 += __shfl_xor(a0, d, 64); a1 += __shfl_xor(a1, d, 64);
    a2 += __shfl_xor(a2, d, 64); a3 += __shfl_xor(a3, d, 64);
    a4 += __shfl_xor(a4, d, 64); a5 += __shfl_xor(a5, d, 64);
    a6 += __shfl_xor(a6, d, 64); a7 += __shfl_xor(a7, d, 64);
  }
  if (lane < 8){
    float4 o0; o0.x = a0; o0.y = a1; o0.z = a2; o0.w = a3;
    float4 o1; o1.x = a4; o1.y = a5; o1.z = a6; o1.w = a7;
    float4* dst = (float4*)(nacc + (size_t)n*64 + (size_t)c8*8);
    dst[0] = o0; dst[1] = o1;
  }
}

// ---------------- fallback msg (separate halves + filt buffer) ----------------
__global__ __launch_bounds__(256) void k_msg3(const unsigned short* __restrict__ gated, int gst, int colBase,
                                              const int4* __restrict__ edat, const float* __restrict__ filt,
                                              const int* __restrict__ offs,
                                              const float* __restrict__ scE, const float* __restrict__ shE,
                                              int scOff, float* __restrict__ nacc, int NN){
  int w = threadIdx.x >> 6, lane = threadIdx.x & 63;
  int n = blockIdx.x*4 + w;
  if (n >= NN) return;
  int sub = lane >> 5, c2 = lane & 31;
  float a0 = 0.f, a1 = 0.f;
  int p0 = offs[n], p1 = offs[n+1];
  for (int p = p0; p < p1; p += 2){
    int idx = p + sub;
    bool ok = idx < p1;
    int q = ok ? idx : p;
    unsigned v = *(const unsigned*)(gated + (size_t)q*gst + colBase + c2*2);
    float f = filt[q];
    int cr = edat[q].w;
    float2 sc2 = *(const float2*)(scE + cr*128 + scOff + c2*2);
    float2 sh2 = *(const float2*)(shE + cr*128 + scOff + c2*2);
    if (ok){
      float g0 = bf2f((unsigned short)(v & 0xffffu));
      float g1 = bf2f((unsigned short)(v >> 16));
      a0 += f*fmaxf(g0*sc2.x + sh2.x, 0.f);
      a1 += f*fmaxf(g1*sc2.y + sh2.y, 0.f);
    }
  }
  a0 += __shfl_xor(a0, 32, 64);
  a1 += __shfl_xor(a1, 32, 64);
  if (lane < 32) *(float2*)(nacc + (size_t)n*64 + (size_t)c2*2) = make_float2(a0, a1);
}

// ---------------- node epilogue: norm + 2x residual MLP + final relu ----------------
__global__ __launch_bounds__(256) void k_final(const float* __restrict__ nacc, const int* __restrict__ ncnt,
                                               const int* __restrict__ cidx, const float* __restrict__ nsc,
                                               const float* __restrict__ nsh, const float* __restrict__ W1a,
                                               const float* __restrict__ W1b, const float* __restrict__ W2a,
                                               const float* __restrict__ W2b, const float* __restrict__ atom,
                                               float* __restrict__ out, int NN)
{
  __shared__ float sW[4][2048];
  __shared__ float hbuf[8192];
  int tid = threadIdx.x;
  for (int i = tid; i < 2048; i += 256){
    sW[0][i] = W1a[i]; sW[1][i] = W1b[i]; sW[2][i] = W2a[i]; sW[3][i] = W2b[i];
  }
  __syncthreads();
  int n = blockIdx.x*256 + tid;
  if (n >= NN) return;
  const float ISQ2 = 0.70710678118654752440f;
  int cr = cidx[n];
  float inv = 1.f / fmaxf((float)ncnt[n], 1.f);
  float x[64];
  const float4* src = (const float4*)(nacc + (size_t)n*64);
#pragma unroll
  for (int j = 0; j < 16; ++j){
    float4 v = src[j];
    x[4*j] = v.x*inv; x[4*j+1] = v.y*inv; x[4*j+2] = v.z*inv; x[4*j+3] = v.w*inv;
  }
#pragma unroll
  for (int c = 0; c < 64; ++c)
    x[c] = x[c]*nsc[cr*64 + c] + nsh[cr*64 + c];

  for (int blk = 0; blk < 2; ++blk){
    const float* sa = sW[blk*2];
    const float* sb = sW[blk*2 + 1];
    for (int j = 0; j < 32; ++j){
      float s = 0.f;
#pragma unroll
      for (int k = 0; k < 64; ++k) s += x[k]*sa[k*32 + j];
      hbuf[tid*32 + (j ^ (tid & 31))] = fmaxf(s, 0.f);
    }
    float x2[64];
#pragma unroll
    for (int c = 0; c < 64; ++c) x2[c] = 0.f;
    for (int j = 0; j < 32; ++j){
      float hj = hbuf[tid*32 + (j ^ (tid & 31))];
#pragma unroll
      for (int c = 0; c < 64; ++c) x2[c] += hj*sb[j*64 + c];
    }
#pragma unroll
    for (int c = 0; c < 64; ++c)
      x[c] = (x[c] + fmaxf(x2[c], 0.f))*ISQ2;
  }
  const float4* ap = (const float4*)(atom + (size_t)n*64);
  float4* op = (float4*)(out + (size_t)n*64);
#pragma unroll
  for (int j = 0; j < 16; ++j){
    float4 av = ap[j]; float4 o;
    o.x = ISQ2*fmaxf(av.x + x[4*j],   0.f);
    o.y = ISQ2*fmaxf(av.y + x[4*j+1], 0.f);
    o.z = ISQ2*fmaxf(av.z + x[4*j+2], 0.f);
    o.w = ISQ2*fmaxf(av.w + x[4*j+3], 0.f);
    op[j] = o;
  }
}

extern "C" void kernel_launch(void* const* d_in, const int* in_sizes, int n_in,
                              void* d_out, int out_size, void* d_ws, size_t ws_size,
                              hipStream_t stream)
{
  const float* atom  = (const float*)d_in[0];
  const float* edgef = (const float*)d_in[1];
  const float* rbff  = (const float*)d_in[2];
  const int*   nbr   = (const int*)d_in[3];
  const int*   cidxn = (const int*)d_in[4];
  const int*   cidxe = (const int*)d_in[5];
  const float* Wrbf  = (const float*)d_in[6];
  const float* Wful  = (const float*)d_in[7];
  const float* Wmask = (const float*)d_in[8];
  const float* g1    = (const float*)d_in[9];
  const float* b1    = (const float*)d_in[10];
  const float* g2    = (const float*)d_in[11];
  const float* b2    = (const float*)d_in[12];
  const float* W1a   = (const float*)d_in[13];
  const float* W1b   = (const float*)d_in[14];
  const float* W2a   = (const float*)d_in[15];
  const float* W2b   = (const float*)d_in[16];
  float* out = (float*)d_out;

  const int E  = in_sizes[1] / 64;
  const int NN = in_sizes[0] / 64;
  const int nT = (E + 15) / 16;

  char* p = (char*)d_ws;
  auto take = [&](size_t bytes){ void* r = (void*)p; p += (bytes + 255) & ~(size_t)255; return r; };

  const bool full = ws_size >= (size_t)360000000;
  const int gstride = full ? 128 : 64;

  unsigned short* gated = (unsigned short*)take((size_t)E*gstride*2);
  float* pstat  = (float*)take((size_t)2048*256*4);
  float* pstatN = (float*)take((size_t)512*128*4);
  float* nacc   = (float*)take((size_t)NN*64*4);
  int*   ncnt   = (int*)take((size_t)NN*4);
  int*   offs   = (int*)take((size_t)(NN+1)*4);
  int*   cursor = (int*)take((size_t)NN*4);
  int4*  edat   = (int4*)take((size_t)E*16);
  int*   celist = (int*)take((size_t)E*4);
  int*   cnlist = (int*)take((size_t)NN*4);
  int*   ceoffs = (int*)take(257*4);
  int*   cecur  = (int*)take(256*4);
  int*   cnoffs = (int*)take(257*4);
  int*   cncur  = (int*)take(256*4);
  int*   ccnte  = (int*)take(1024);
  int*   ccntn  = (int*)take(1024);
  float* scE    = (float*)take(256*128*4);
  float* shE    = (float*)take(256*128*4);
  float* nsc    = (float*)take(256*64*4);
  float* nsh    = (float*)take(256*64*4);
  float* w2     = (float*)take(256*64*4);
  float* fb     = (float*)take(256*4);
  float* filt   = (float*)take((size_t)E*4);
  unsigned short* Bpack = (unsigned short*)take(6*8*64*8*2);

  (void)hipMemsetAsync(ncnt,  0, (size_t)NN*4, stream);
  (void)hipMemsetAsync(ccnte, 0, 1024, stream);
  (void)hipMemsetAsync(ccntn, 0, 1024, stream);

  k_prep<<<48, 64, 0, stream>>>(Wful, Bpack);
  k_pre<<<2048, 256, 0, stream>>>(cidxe, E, cidxn, NN, nbr, ccnte, ccntn, ncnt);
  k_scans<<<3, 1024, 0, stream>>>(ncnt, NN, offs, cursor, ccnte, ccntn, ceoffs, cecur, cnoffs, cncur);
  k_scatter2<<<(E + 1023)/1024, 256, 0, stream>>>(nbr, cidxe, E, cursor, edat, cecur, celist);
  k_cscatter<<<(NN + 4095)/4096, 256, 0, stream>>>(cidxn, NN, cncur, cnlist);

  if (full){
    k_gemm<0,8><<<1024, 512, 0, stream>>>(atom, edgef, rbff, edat, Wrbf, Bpack, gated, 128, 0, nT, E);
    k_cstats128<<<2048, 256, 0, stream>>>(gated, ceoffs, celist, pstat);
    k_red128f<<<128, 256, 0, stream>>>(pstat, ccnte, g1, b1, Wmask, scE, shE, w2, fb);
    k_msgf8<<<(NN + 3)/4, 256, 0, stream>>>(gated, edat, offs, scE, shE, w2, fb, nacc, NN);
  } else {
    k_gemm<0,4><<<1024, 512, 0, stream>>>(atom, edgef, rbff, edat, Wrbf, Bpack, gated, 64, 0, nT, E);
    k_cstats64<<<2048, 256, 0, stream>>>(gated, ceoffs, celist, pstat);
    k_red64<<<64, 256, 0, stream>>>(pstat, 8, ccnte, g1, b1, scE, shE, 128, 0);
    k_fprep<<<64, 256, 0, stream>>>(scE, shE, Wmask, w2, fb);
    k_filter<<<(E + 255)/256, 256, 0, stream>>>(gated, 64, edat, w2, fb, filt, E);
    k_gemm<4,8><<<1024, 512, 0, stream>>>(atom, edgef, rbff, edat, Wrbf, Bpack, gated, 64, 64, nT, E);
    k_cstats64<<<2048, 256, 0, stream>>>(gated, ceoffs, celist, pstat);
    k_red64<<<64, 256, 0, stream>>>(pstat, 8, ccnte, g1 + 64, b1 + 64, scE, shE, 128, 64);
    k_msg3<<<(NN + 3)/4, 256, 0, stream>>>(gated, 64, 0, edat, filt, offs, scE, shE, 64, nacc, NN);
  }

  k_cnstats<<<512, 256, 0, stream>>>(nacc, ncnt, cnoffs, cnlist, pstatN);
  k_red64<<<64, 256, 0, stream>>>(pstatN, 2, ccntn, g2, b2, nsc, nsh, 64, 0);
  k_final<<<(NN + 255)/256, 256, 0, stream>>>(nacc, ncnt, cidxn, nsc, nsh, W1a, W1b, W2a, W2b, atom, out, NN);
}